// Round 2
// baseline (1720.135 us; speedup 1.0000x reference)
//
#include <hip/hip_runtime.h>

#define N_U   50000
#define N_I   50000
#define DIM   64
#define B_USERS 1024
#define P_POS 10
#define N_NEG 40

// E[i] = src[i]; S[i] = src[i]
__global__ void init_copy(const float* __restrict__ src, float* __restrict__ E,
                          float* __restrict__ S, int n) {
    int i = blockIdx.x * blockDim.x + threadIdx.x;
    if (i < n) { float v = src[i]; E[i] = v; S[i] = v; }
}

// Wave-per-edge SpMM for both A and A^T in one pass.
// lane = dim. Gathers are coalesced 256B per wave; scatters are f32 atomics.
__global__ void spmm_both(const float* __restrict__ vals, const int* __restrict__ rows,
                          const int* __restrict__ cols, const float* __restrict__ Eu,
                          const float* __restrict__ Ei, float* __restrict__ Zu,
                          float* __restrict__ Zi, int nnz) {
    int gid  = blockIdx.x * blockDim.x + threadIdx.x;
    int e    = gid >> 6;
    int lane = gid & 63;
    if (e >= nnz) return;
    float v = vals[e];
    int r = rows[e];
    int c = cols[e];
    float ei = Ei[c * DIM + lane];
    float eu = Eu[r * DIM + lane];
    atomicAdd(&Zu[r * DIM + lane], v * ei);
    atomicAdd(&Zi[c * DIM + lane], v * eu);
}

// E += leaky(Z); S += E   (leaky slope 0.5)
__global__ void leaky_update(float* __restrict__ E, const float* __restrict__ Z,
                             float* __restrict__ S, int n) {
    int i = blockIdx.x * blockDim.x + threadIdx.x;
    if (i < n) {
        float z = Z[i];
        z = (z > 0.0f) ? z : 0.5f * z;
        float e = E[i] + z;
        E[i] = e;
        S[i] += e;
    }
}

// One wave per user. lane = dim. Dot products via 6-step shfl_xor reduce.
__global__ __launch_bounds__(256) void loss_kernel(const float* __restrict__ Su,
                                                   const float* __restrict__ Si,
                                                   const int* __restrict__ uids,
                                                   const int* __restrict__ pos,
                                                   const int* __restrict__ neg,
                                                   float* __restrict__ acc) {
    int wid  = (blockIdx.x * blockDim.x + threadIdx.x) >> 6;  // user index
    int lane = threadIdx.x & 63;
    if (wid >= B_USERS) return;

    int uid = uids[wid];
    float u = Su[uid * DIM + lane];

    float pos_min = 1e30f, pos_h = 0.0f;
    for (int p = 0; p < P_POS; ++p) {
        int it = pos[wid * P_POS + p];
        float s = u * Si[it * DIM + lane];
        #pragma unroll
        for (int o = 32; o > 0; o >>= 1) s += __shfl_xor(s, o, 64);
        pos_min = fminf(pos_min, s);
        pos_h  += fmaxf(1.0f - s, 0.0f);
    }

    float neg_max = -1e30f, neg_h = 0.0f;
    for (int n = 0; n < N_NEG; ++n) {
        int it = neg[wid * N_NEG + n];
        float s = u * Si[it * DIM + lane];
        #pragma unroll
        for (int o = 32; o > 0; o >>= 1) s += __shfl_xor(s, o, 64);
        neg_max = fmaxf(neg_max, s);
        neg_h  += fmaxf(s - 0.5f, 0.0f);
    }

    // sum(cumsum(delta)) = sum_j delta[j] * (B - j)
    float delta = (neg_max - pos_min > 0.005f) ? 10.0f * (pos_min - neg_max) : 0.0f;
    float contrib = pos_h + (float)P_POS * neg_h + delta * (float)(B_USERS - wid);
    if (lane == 0) atomicAdd(acc, contrib);
}

__global__ void finalize(const float* __restrict__ acc, float* __restrict__ out) {
    out[0] = acc[0] / (float)B_USERS + 0.2f;
}

extern "C" void kernel_launch(void* const* d_in, const int* in_sizes, int n_in,
                              void* d_out, int out_size, void* d_ws, size_t ws_size,
                              hipStream_t stream) {
    const float* Eu0  = (const float*)d_in[0];
    const float* Ei0  = (const float*)d_in[1];
    const float* vals = (const float*)d_in[2];
    // d_in[3..6] = u_mul_s, vt, v_mul_s, ut : dead code in the reference loss
    const int* rows = (const int*)d_in[7];
    const int* cols = (const int*)d_in[8];
    const int* uids = (const int*)d_in[9];
    const int* pos  = (const int*)d_in[10];
    const int* neg  = (const int*)d_in[11];
    int nnz = in_sizes[2];

    const int nf = N_U * DIM;  // == N_I * DIM
    float* ws  = (float*)d_ws;
    float* E_u = ws;
    float* E_i = E_u + nf;
    float* Z_u = E_i + nf;
    float* Z_i = Z_u + nf;
    float* S_u = Z_i + nf;
    float* S_i = S_u + nf;
    float* acc = S_i + nf;

    const int blk = 256;
    const int gn  = (nf + blk - 1) / blk;

    init_copy<<<gn, blk, 0, stream>>>(Eu0, E_u, S_u, nf);
    init_copy<<<gn, blk, 0, stream>>>(Ei0, E_i, S_i, nf);
    hipMemsetAsync(acc, 0, sizeof(float), stream);

    for (int layer = 0; layer < 2; ++layer) {
        hipMemsetAsync(Z_u, 0, (size_t)nf * sizeof(float), stream);
        hipMemsetAsync(Z_i, 0, (size_t)nf * sizeof(float), stream);
        int threads = nnz * 64;
        spmm_both<<<(threads + blk - 1) / blk, blk, 0, stream>>>(
            vals, rows, cols, E_u, E_i, Z_u, Z_i, nnz);
        leaky_update<<<gn, blk, 0, stream>>>(E_u, Z_u, S_u, nf);
        leaky_update<<<gn, blk, 0, stream>>>(E_i, Z_i, S_i, nf);
    }

    loss_kernel<<<(B_USERS * 64) / 256, 256, 0, stream>>>(S_u, S_i, uids, pos, neg, acc);
    finalize<<<1, 1, 0, stream>>>(acc, (float*)d_out);
}

// Round 3
// 1022.218 us; speedup vs baseline: 1.6827x; 1.6827x over previous
//
#include <hip/hip_runtime.h>

#define N_U   50000
#define N_I   50000
#define NSEG  (N_U + N_I)      // row segments then col segments
#define DIM   64
#define B_USERS 1024
#define P_POS 10
#define N_NEG 40

// ---------------- CSR build ----------------

__global__ void k_hist(const int* __restrict__ rows, const int* __restrict__ cols,
                       int* __restrict__ cnt, int nnz) {
    int e = blockIdx.x * blockDim.x + threadIdx.x;
    if (e >= nnz) return;
    atomicAdd(&cnt[rows[e]], 1);
    atomicAdd(&cnt[N_U + cols[e]], 1);
}

// level-1 scan: 1024 elems per block (256 thr x 4)
__global__ __launch_bounds__(256) void k_scan1(const int* __restrict__ cnt,
                                               int* __restrict__ off,
                                               int* __restrict__ bsum, int n) {
    __shared__ int sh[256];
    int b = blockIdx.x, t = threadIdx.x;
    int base = b * 1024 + t * 4;
    int v0 = (base + 0 < n) ? cnt[base + 0] : 0;
    int v1 = (base + 1 < n) ? cnt[base + 1] : 0;
    int v2 = (base + 2 < n) ? cnt[base + 2] : 0;
    int v3 = (base + 3 < n) ? cnt[base + 3] : 0;
    int tsum = v0 + v1 + v2 + v3;
    sh[t] = tsum;
    __syncthreads();
    for (int o = 1; o < 256; o <<= 1) {
        int x = (t >= o) ? sh[t - o] : 0;
        __syncthreads();
        sh[t] += x;
        __syncthreads();
    }
    int excl = sh[t] - tsum;
    if (t == 255) bsum[b] = sh[255];
    if (base + 0 < n) off[base + 0] = excl;
    if (base + 1 < n) off[base + 1] = excl + v0;
    if (base + 2 < n) off[base + 2] = excl + v0 + v1;
    if (base + 3 < n) off[base + 3] = excl + v0 + v1 + v2;
}

// level-2: exclusive scan of block sums (nb <= 128), one block of 128
__global__ void k_scan2(int* bsum, int nb) {
    __shared__ int sh[128];
    int t = threadIdx.x;
    int v = (t < nb) ? bsum[t] : 0;
    sh[t] = v;
    __syncthreads();
    for (int o = 1; o < 128; o <<= 1) {
        int x = (t >= o) ? sh[t - o] : 0;
        __syncthreads();
        sh[t] += x;
        __syncthreads();
    }
    if (t < nb) bsum[t] = sh[t] - v;
}

__global__ void k_scan3(int* __restrict__ off, const int* __restrict__ bsum, int n) {
    int i = blockIdx.x * blockDim.x + threadIdx.x;
    if (i < n) off[i] += bsum[i >> 10];
}

// scatter edges into CSR order; mutates off[] -> segment END offsets
// row segment r stores (N_U + c, val): gathers from item side
// col segment c stores (r, val):        gathers from user side
__global__ void k_scatter(const float* __restrict__ vals, const int* __restrict__ rows,
                          const int* __restrict__ cols, int* __restrict__ cur,
                          int2* __restrict__ edges, int nnz) {
    int e = blockIdx.x * blockDim.x + threadIdx.x;
    if (e >= nnz) return;
    int r = rows[e], c = cols[e];
    int vb = __float_as_int(vals[e]);
    int sr = atomicAdd(&cur[r], 1);
    int2 er; er.x = N_U + c; er.y = vb;
    edges[sr] = er;
    int sc = atomicAdd(&cur[N_U + c], 1);
    int2 ec; ec.x = r; ec.y = vb;
    edges[sc] = ec;
}

// ---------------- propagation: one wave per segment, lane = dim ----------------
// E_next[s] = E_cur[s] + leaky(sum val * E_cur[nbr])
template <int FIRST>
__global__ __launch_bounds__(256) void k_prop(const int2* __restrict__ edges,
                                              const int* __restrict__ endo,
                                              const int* __restrict__ cnt,
                                              const float* __restrict__ Eu0,
                                              const float* __restrict__ Ei0,
                                              const float* __restrict__ Ecur,
                                              float* __restrict__ Enext) {
    int seg  = (blockIdx.x * blockDim.x + threadIdx.x) >> 6;
    int lane = threadIdx.x & 63;
    if (seg >= NSEG) return;
    int end = endo[seg], n = cnt[seg], start = end - n;

    float acc = 0.0f;
    for (int b = 0; b < n; b += 64) {
        int k = b + lane;
        int2 ed = make_int2(0, 0);
        if (k < n) ed = edges[start + k];
        int m = min(n - b, 64);
        for (int j = 0; j < m; ++j) {
            int idx = __shfl(ed.x, j, 64);
            float v = __int_as_float(__shfl(ed.y, j, 64));
            const float* src;
            if (FIRST) src = (idx < N_U) ? (Eu0 + (size_t)idx * DIM)
                                         : (Ei0 + (size_t)(idx - N_U) * DIM);
            else       src = Ecur + (size_t)idx * DIM;
            acc += v * src[lane];
        }
    }

    float eo;
    if (FIRST) eo = (seg < N_U) ? Eu0[(size_t)seg * DIM + lane]
                                : Ei0[(size_t)(seg - N_U) * DIM + lane];
    else       eo = Ecur[(size_t)seg * DIM + lane];
    float en = eo + (acc > 0.0f ? acc : 0.5f * acc);
    Enext[(size_t)seg * DIM + lane] = en;
}

// ---------------- loss: one wave per user; S reconstructed on the fly ----------------
__global__ __launch_bounds__(256) void k_loss(const float* __restrict__ Eu0,
                                              const float* __restrict__ Ei0,
                                              const float* __restrict__ E1,
                                              const float* __restrict__ E2,
                                              const int* __restrict__ uids,
                                              const int* __restrict__ pos,
                                              const int* __restrict__ neg,
                                              float* __restrict__ acc) {
    int wid  = (blockIdx.x * blockDim.x + threadIdx.x) >> 6;
    int lane = threadIdx.x & 63;
    if (wid >= B_USERS) return;

    int uid = uids[wid];
    float u = Eu0[(size_t)uid * DIM + lane]
            + E1[(size_t)uid * DIM + lane]
            + E2[(size_t)uid * DIM + lane];

    float pos_min = 1e30f, pos_h = 0.0f;
    for (int p = 0; p < P_POS; ++p) {
        int it = pos[wid * P_POS + p];
        int g  = N_U + it;
        float si = Ei0[(size_t)it * DIM + lane]
                 + E1[(size_t)g * DIM + lane]
                 + E2[(size_t)g * DIM + lane];
        float s = u * si;
        #pragma unroll
        for (int o = 32; o > 0; o >>= 1) s += __shfl_xor(s, o, 64);
        pos_min = fminf(pos_min, s);
        pos_h  += fmaxf(1.0f - s, 0.0f);
    }

    float neg_max = -1e30f, neg_h = 0.0f;
    for (int nn = 0; nn < N_NEG; ++nn) {
        int it = neg[wid * N_NEG + nn];
        int g  = N_U + it;
        float si = Ei0[(size_t)it * DIM + lane]
                 + E1[(size_t)g * DIM + lane]
                 + E2[(size_t)g * DIM + lane];
        float s = u * si;
        #pragma unroll
        for (int o = 32; o > 0; o >>= 1) s += __shfl_xor(s, o, 64);
        neg_max = fmaxf(neg_max, s);
        neg_h  += fmaxf(s - 0.5f, 0.0f);
    }

    float delta = (neg_max - pos_min > 0.005f) ? 10.0f * (pos_min - neg_max) : 0.0f;
    float contrib = pos_h + (float)P_POS * neg_h + delta * (float)(B_USERS - wid);
    if (lane == 0) atomicAdd(acc, contrib);
}

__global__ void finalize(const float* __restrict__ acc, float* __restrict__ out) {
    out[0] = acc[0] / (float)B_USERS + 0.2f;
}

extern "C" void kernel_launch(void* const* d_in, const int* in_sizes, int n_in,
                              void* d_out, int out_size, void* d_ws, size_t ws_size,
                              hipStream_t stream) {
    const float* Eu0  = (const float*)d_in[0];
    const float* Ei0  = (const float*)d_in[1];
    const float* vals = (const float*)d_in[2];
    // d_in[3..6] dead (SVD branch unused by the loss)
    const int* rows = (const int*)d_in[7];
    const int* cols = (const int*)d_in[8];
    const int* uids = (const int*)d_in[9];
    const int* pos  = (const int*)d_in[10];
    const int* neg  = (const int*)d_in[11];
    int nnz = in_sizes[2];

    // workspace layout (edges first for 8B alignment)
    int2*  edges = (int2*)d_ws;                         // 2*nnz
    float* E1    = (float*)(edges + (size_t)2 * nnz);   // NSEG*DIM
    float* E2    = E1 + (size_t)NSEG * DIM;
    int*   cnt   = (int*)(E2 + (size_t)NSEG * DIM);     // NSEG
    int*   off   = cnt + NSEG;                          // NSEG
    int*   bsum  = off + NSEG;                          // 128
    float* acc   = (float*)(bsum + 128);

    const int blk = 256;
    const int nb_scan1 = (NSEG + 1023) / 1024;          // 98

    hipMemsetAsync(cnt, 0, (size_t)NSEG * sizeof(int), stream);
    hipMemsetAsync(acc, 0, sizeof(float), stream);

    k_hist<<<(nnz + blk - 1) / blk, blk, 0, stream>>>(rows, cols, cnt, nnz);
    k_scan1<<<nb_scan1, blk, 0, stream>>>(cnt, off, bsum, NSEG);
    k_scan2<<<1, 128, 0, stream>>>(bsum, nb_scan1);
    k_scan3<<<(NSEG + blk - 1) / blk, blk, 0, stream>>>(off, bsum, NSEG);
    k_scatter<<<(nnz + blk - 1) / blk, blk, 0, stream>>>(vals, rows, cols, off, edges, nnz);

    const int prop_blocks = (NSEG * 64 + blk - 1) / blk;   // 25000
    k_prop<1><<<prop_blocks, blk, 0, stream>>>(edges, off, cnt, Eu0, Ei0, nullptr, E1);
    k_prop<0><<<prop_blocks, blk, 0, stream>>>(edges, off, cnt, Eu0, Ei0, E1, E2);

    k_loss<<<(B_USERS * 64) / blk, blk, 0, stream>>>(Eu0, Ei0, E1, E2, uids, pos, neg, acc);
    finalize<<<1, 1, 0, stream>>>(acc, (float*)d_out);
}

// Round 4
// 819.066 us; speedup vs baseline: 2.1001x; 1.2480x over previous
//
#include <hip/hip_runtime.h>

#define N_U   50000
#define N_I   50000
#define NSEG  (N_U + N_I)      // row segments then col segments
#define DIM   64
#define B_USERS 1024
#define P_POS 10
#define N_NEG 40

// f32 -> bf16 bits (RNE)
__device__ __forceinline__ unsigned f2b(float f) {
    unsigned b = __float_as_uint(f);
    return (b + 0x7FFFu + ((b >> 16) & 1u)) >> 16;
}
// 16-bit bf16 pattern -> f32
__device__ __forceinline__ float b2f(unsigned u) {
    return __uint_as_float(u << 16);
}

// ---- convert Eu0||Ei0 (f32) into one concatenated bf16 table ----
__global__ void k_conv(const float* __restrict__ Eu0, const float* __restrict__ Ei0,
                       ushort* __restrict__ E0b) {
    int p = blockIdx.x * blockDim.x + threadIdx.x;   // pair index (2 dims)
    if (p >= NSEG * (DIM / 2)) return;
    float2 v = (p < N_U * (DIM / 2)) ? ((const float2*)Eu0)[p]
                                     : ((const float2*)Ei0)[p - N_U * (DIM / 2)];
    ushort2 o;
    o.x = (ushort)f2b(v.x);
    o.y = (ushort)f2b(v.y);
    ((ushort2*)E0b)[p] = o;
}

// ---------------- CSR build ----------------
__global__ void k_hist(const int* __restrict__ rows, const int* __restrict__ cols,
                       int* __restrict__ cnt, int nnz) {
    int e = blockIdx.x * blockDim.x + threadIdx.x;
    if (e >= nnz) return;
    atomicAdd(&cnt[rows[e]], 1);
    atomicAdd(&cnt[N_U + cols[e]], 1);
}

__global__ __launch_bounds__(256) void k_scan1(const int* __restrict__ cnt,
                                               int* __restrict__ off,
                                               int* __restrict__ bsum, int n) {
    __shared__ int sh[256];
    int b = blockIdx.x, t = threadIdx.x;
    int base = b * 1024 + t * 4;
    int v0 = (base + 0 < n) ? cnt[base + 0] : 0;
    int v1 = (base + 1 < n) ? cnt[base + 1] : 0;
    int v2 = (base + 2 < n) ? cnt[base + 2] : 0;
    int v3 = (base + 3 < n) ? cnt[base + 3] : 0;
    int tsum = v0 + v1 + v2 + v3;
    sh[t] = tsum;
    __syncthreads();
    for (int o = 1; o < 256; o <<= 1) {
        int x = (t >= o) ? sh[t - o] : 0;
        __syncthreads();
        sh[t] += x;
        __syncthreads();
    }
    int excl = sh[t] - tsum;
    if (t == 255) bsum[b] = sh[255];
    if (base + 0 < n) off[base + 0] = excl;
    if (base + 1 < n) off[base + 1] = excl + v0;
    if (base + 2 < n) off[base + 2] = excl + v0 + v1;
    if (base + 3 < n) off[base + 3] = excl + v0 + v1 + v2;
}

__global__ void k_scan2(int* bsum, int nb) {
    __shared__ int sh[128];
    int t = threadIdx.x;
    int v = (t < nb) ? bsum[t] : 0;
    sh[t] = v;
    __syncthreads();
    for (int o = 1; o < 128; o <<= 1) {
        int x = (t >= o) ? sh[t - o] : 0;
        __syncthreads();
        sh[t] += x;
        __syncthreads();
    }
    if (t < nb) bsum[t] = sh[t] - v;
}

__global__ void k_scan3(int* __restrict__ off, const int* __restrict__ bsum, int n) {
    int i = blockIdx.x * blockDim.x + threadIdx.x;
    if (i < n) off[i] += bsum[i >> 10];
}

// scatter packed edges: [31:15] neighbor idx (17b), [14:0] val (f32 bits 30:16)
__global__ void k_scatter(const float* __restrict__ vals, const int* __restrict__ rows,
                          const int* __restrict__ cols, int* __restrict__ cur,
                          unsigned* __restrict__ edges, int nnz) {
    int e = blockIdx.x * blockDim.x + threadIdx.x;
    if (e >= nnz) return;
    unsigned b = __float_as_uint(vals[e]);
    unsigned v15 = ((b + 0x7FFFu + ((b >> 16) & 1u)) >> 16) & 0x7FFFu;
    int r = rows[e], c = cols[e];
    int sr = atomicAdd(&cur[r], 1);
    edges[sr] = (((unsigned)(N_U + c)) << 15) | v15;
    int sc = atomicAdd(&cur[N_U + c], 1);
    edges[sc] = (((unsigned)r) << 15) | v15;
}

// ---------------- propagation: one wave per segment, 2 edges/iter ----------------
// Enext[s] = Ecur[s] + leaky(sum val * Ecur[nbr]); bf16 in/out, f32 accumulate
__global__ __launch_bounds__(256) void k_prop(const unsigned* __restrict__ edges,
                                              const int* __restrict__ endo,
                                              const int* __restrict__ cnt,
                                              const ushort* __restrict__ Ecur,
                                              ushort* __restrict__ Enext) {
    int seg  = (blockIdx.x * blockDim.x + threadIdx.x) >> 6;
    int lane = threadIdx.x & 63;
    if (seg >= NSEG) return;
    int end = endo[seg], n = cnt[seg], start = end - n;
    int half = lane >> 5;   // lanes 0-31 take edge j, 32-63 take edge j+1
    int l31  = lane & 31;

    float ax = 0.0f, ay = 0.0f;
    for (int b = 0; b < n; b += 64) {
        int k = b + lane;
        unsigned pk = (k < n) ? edges[start + k] : 0u;   // lane>=m holds 0 -> idx 0, v forced 0
        int m = min(n - b, 64);
        for (int j = 0; j < m; j += 2) {
            int sel = j + half;
            unsigned pj = __shfl(pk, sel, 64);
            float v = (sel < m) ? __uint_as_float((pj & 0x7FFFu) << 16) : 0.0f;
            unsigned idx = pj >> 15;
            ushort2 ev = ((const ushort2*)(Ecur + (size_t)idx * DIM))[l31];
            ax = fmaf(v, b2f(ev.x), ax);
            ay = fmaf(v, b2f(ev.y), ay);
        }
    }
    ax += __shfl_xor(ax, 32, 64);
    ay += __shfl_xor(ay, 32, 64);
    if (half == 0) {
        ushort2 ec = ((const ushort2*)(Ecur + (size_t)seg * DIM))[l31];
        float zx = ax > 0.0f ? ax : 0.5f * ax;
        float zy = ay > 0.0f ? ay : 0.5f * ay;
        ushort2 o;
        o.x = (ushort)f2b(b2f(ec.x) + zx);
        o.y = (ushort)f2b(b2f(ec.y) + zy);
        ((ushort2*)(Enext + (size_t)seg * DIM))[l31] = o;
    }
}

// ---------------- loss: one wave per user; S = E0+E1+E2 on the fly ----------------
__global__ __launch_bounds__(256) void k_loss(const ushort* __restrict__ E0,
                                              const ushort* __restrict__ E1,
                                              const ushort* __restrict__ E2,
                                              const int* __restrict__ uids,
                                              const int* __restrict__ pos,
                                              const int* __restrict__ neg,
                                              float* __restrict__ acc) {
    int wid  = (blockIdx.x * blockDim.x + threadIdx.x) >> 6;
    int lane = threadIdx.x & 63;
    if (wid >= B_USERS) return;

    int uid = uids[wid];
    size_t ub = (size_t)uid * DIM + lane;
    float u = b2f(E0[ub]) + b2f(E1[ub]) + b2f(E2[ub]);

    float pos_min = 1e30f, pos_h = 0.0f;
    for (int p = 0; p < P_POS; ++p) {
        int it = pos[wid * P_POS + p];
        size_t ib = (size_t)(N_U + it) * DIM + lane;
        float si = b2f(E0[ib]) + b2f(E1[ib]) + b2f(E2[ib]);
        float s = u * si;
        #pragma unroll
        for (int o = 32; o > 0; o >>= 1) s += __shfl_xor(s, o, 64);
        pos_min = fminf(pos_min, s);
        pos_h  += fmaxf(1.0f - s, 0.0f);
    }

    float neg_max = -1e30f, neg_h = 0.0f;
    for (int nn = 0; nn < N_NEG; ++nn) {
        int it = neg[wid * N_NEG + nn];
        size_t ib = (size_t)(N_U + it) * DIM + lane;
        float si = b2f(E0[ib]) + b2f(E1[ib]) + b2f(E2[ib]);
        float s = u * si;
        #pragma unroll
        for (int o = 32; o > 0; o >>= 1) s += __shfl_xor(s, o, 64);
        neg_max = fmaxf(neg_max, s);
        neg_h  += fmaxf(s - 0.5f, 0.0f);
    }

    float delta = (neg_max - pos_min > 0.005f) ? 10.0f * (pos_min - neg_max) : 0.0f;
    float contrib = pos_h + (float)P_POS * neg_h + delta * (float)(B_USERS - wid);
    if (lane == 0) atomicAdd(acc, contrib);
}

__global__ void finalize(const float* __restrict__ acc, float* __restrict__ out) {
    out[0] = acc[0] / (float)B_USERS + 0.2f;
}

extern "C" void kernel_launch(void* const* d_in, const int* in_sizes, int n_in,
                              void* d_out, int out_size, void* d_ws, size_t ws_size,
                              hipStream_t stream) {
    const float* Eu0  = (const float*)d_in[0];
    const float* Ei0  = (const float*)d_in[1];
    const float* vals = (const float*)d_in[2];
    // d_in[3..6] dead (SVD branch unused by the loss)
    const int* rows = (const int*)d_in[7];
    const int* cols = (const int*)d_in[8];
    const int* uids = (const int*)d_in[9];
    const int* pos  = (const int*)d_in[10];
    const int* neg  = (const int*)d_in[11];
    int nnz = in_sizes[2];

    // workspace layout
    unsigned* edges = (unsigned*)d_ws;                       // 2*nnz u32
    ushort*   E0b   = (ushort*)(edges + (size_t)2 * nnz);    // NSEG*DIM bf16
    ushort*   E1b   = E0b + (size_t)NSEG * DIM;
    ushort*   E2b   = E1b + (size_t)NSEG * DIM;
    int*      cnt   = (int*)(E2b + (size_t)NSEG * DIM);      // NSEG
    int*      off   = cnt + NSEG;                            // NSEG
    int*      bsum  = off + NSEG;                            // 128
    float*    acc   = (float*)(bsum + 128);

    const int blk = 256;
    const int nb_scan1 = (NSEG + 1023) / 1024;               // 98

    hipMemsetAsync(cnt, 0, (size_t)NSEG * sizeof(int), stream);
    hipMemsetAsync(acc, 0, sizeof(float), stream);

    k_conv<<<(NSEG * (DIM / 2) + blk - 1) / blk, blk, 0, stream>>>(Eu0, Ei0, E0b);
    k_hist<<<(nnz + blk - 1) / blk, blk, 0, stream>>>(rows, cols, cnt, nnz);
    k_scan1<<<nb_scan1, blk, 0, stream>>>(cnt, off, bsum, NSEG);
    k_scan2<<<1, 128, 0, stream>>>(bsum, nb_scan1);
    k_scan3<<<(NSEG + blk - 1) / blk, blk, 0, stream>>>(off, bsum, NSEG);
    k_scatter<<<(nnz + blk - 1) / blk, blk, 0, stream>>>(vals, rows, cols, off, edges, nnz);

    const int prop_blocks = (NSEG * 64 + blk - 1) / blk;     // 25000
    k_prop<<<prop_blocks, blk, 0, stream>>>(edges, off, cnt, E0b, E1b);
    k_prop<<<prop_blocks, blk, 0, stream>>>(edges, off, cnt, E1b, E2b);

    k_loss<<<(B_USERS * 64) / blk, blk, 0, stream>>>(E0b, E1b, E2b, uids, pos, neg, acc);
    finalize<<<1, 1, 0, stream>>>(acc, (float*)d_out);
}

// Round 5
// 694.901 us; speedup vs baseline: 2.4754x; 1.1787x over previous
//
#include <hip/hip_runtime.h>

#define N_U   50000
#define N_I   50000
#define NSEG  (N_U + N_I)      // row segments then col segments
#define DIM   64
#define B_USERS 1024
#define P_POS 10
#define N_NEG 40

#define BSEG    128                      // segments per bucket
#define NBUK    ((NSEG + BSEG - 1) / BSEG)   // 782
#define NSTRIPE 8
#define SUBCAP  1024                     // capacity per sub-bucket (mean 640, +15 sigma)

// f32 -> bf16 bits (RNE)
__device__ __forceinline__ unsigned f2b(float f) {
    unsigned b = __float_as_uint(f);
    return (b + 0x7FFFu + ((b >> 16) & 1u)) >> 16;
}
__device__ __forceinline__ float b2f(unsigned u) {
    return __uint_as_float(u << 16);
}

// ---- convert Eu0||Ei0 (f32) into one concatenated bf16 table ----
__global__ void k_conv(const float* __restrict__ Eu0, const float* __restrict__ Ei0,
                       ushort* __restrict__ E0b) {
    int p = blockIdx.x * blockDim.x + threadIdx.x;
    if (p >= NSEG * (DIM / 2)) return;
    float2 v = (p < N_U * (DIM / 2)) ? ((const float2*)Eu0)[p]
                                     : ((const float2*)Ei0)[p - N_U * (DIM / 2)];
    ushort2 o;
    o.x = (ushort)f2b(v.x);
    o.y = (ushort)f2b(v.y);
    ((ushort2*)E0b)[p] = o;
}

// ---------------- CSR build ----------------
__global__ void k_hist(const int* __restrict__ rows, const int* __restrict__ cols,
                       int* __restrict__ cnt, int nnz) {
    int e = blockIdx.x * blockDim.x + threadIdx.x;
    if (e >= nnz) return;
    atomicAdd(&cnt[rows[e]], 1);
    atomicAdd(&cnt[N_U + cols[e]], 1);
}

__global__ __launch_bounds__(256) void k_scan1(const int* __restrict__ cnt,
                                               int* __restrict__ off,
                                               int* __restrict__ bsum, int n) {
    __shared__ int sh[256];
    int b = blockIdx.x, t = threadIdx.x;
    int base = b * 1024 + t * 4;
    int v0 = (base + 0 < n) ? cnt[base + 0] : 0;
    int v1 = (base + 1 < n) ? cnt[base + 1] : 0;
    int v2 = (base + 2 < n) ? cnt[base + 2] : 0;
    int v3 = (base + 3 < n) ? cnt[base + 3] : 0;
    int tsum = v0 + v1 + v2 + v3;
    sh[t] = tsum;
    __syncthreads();
    for (int o = 1; o < 256; o <<= 1) {
        int x = (t >= o) ? sh[t - o] : 0;
        __syncthreads();
        sh[t] += x;
        __syncthreads();
    }
    int excl = sh[t] - tsum;
    if (t == 255) bsum[b] = sh[255];
    if (base + 0 < n) off[base + 0] = excl;
    if (base + 1 < n) off[base + 1] = excl + v0;
    if (base + 2 < n) off[base + 2] = excl + v0 + v1;
    if (base + 3 < n) off[base + 3] = excl + v0 + v1 + v2;
}

__global__ void k_scan2(int* bsum, int nb) {
    __shared__ int sh[128];
    int t = threadIdx.x;
    int v = (t < nb) ? bsum[t] : 0;
    sh[t] = v;
    __syncthreads();
    for (int o = 1; o < 128; o <<= 1) {
        int x = (t >= o) ? sh[t - o] : 0;
        __syncthreads();
        sh[t] += x;
        __syncthreads();
    }
    if (t < nb) bsum[t] = sh[t] - v;
}

__global__ void k_scan3(int* __restrict__ off, const int* __restrict__ bsum, int n) {
    int i = blockIdx.x * blockDim.x + threadIdx.x;
    if (i < n) off[i] += bsum[i >> 10];
}

// ---- phase A: bin edges into bucket staging (append, XCD-striped) ----
// record: x = packed edge (nbr<<15 | val15), y = dest segment
__global__ void k_binA(const float* __restrict__ vals, const int* __restrict__ rows,
                       const int* __restrict__ cols, int* __restrict__ tails,
                       uint2* __restrict__ stage, int nnz) {
    int e = blockIdx.x * blockDim.x + threadIdx.x;
    if (e >= nnz) return;
    int stripe = blockIdx.x & (NSTRIPE - 1);
    unsigned b = __float_as_uint(vals[e]);
    unsigned v15 = ((b + 0x7FFFu + ((b >> 16) & 1u)) >> 16) & 0x7FFFu;
    int r = rows[e];
    int g = N_U + cols[e];

    int b1 = r >> 7;
    int s1 = atomicAdd(&tails[b1 * NSTRIPE + stripe], 1);
    uint2 rec1; rec1.x = (((unsigned)g) << 15) | v15; rec1.y = (unsigned)r;
    stage[((size_t)b1 * NSTRIPE + stripe) * SUBCAP + s1] = rec1;

    int b2 = g >> 7;
    int s2 = atomicAdd(&tails[b2 * NSTRIPE + stripe], 1);
    uint2 rec2; rec2.x = (((unsigned)r) << 15) | v15; rec2.y = (unsigned)g;
    stage[((size_t)b2 * NSTRIPE + stripe) * SUBCAP + s2] = rec2;
}

// ---- phase B: per bucket, place staged records at final CSR positions ----
// off[] holds segment starts on entry, segment ENDs on exit (k_prop wants ends)
__global__ __launch_bounds__(256) void k_binB(const uint2* __restrict__ stage,
                                              const int* __restrict__ tails,
                                              int* __restrict__ off,
                                              unsigned* __restrict__ edges) {
    int b = blockIdx.x;
    int t = threadIdx.x;
    __shared__ int cur[BSEG];
    int seg0 = b * BSEG;
    int nh = min(BSEG, NSEG - seg0);
    if (t < nh) cur[t] = off[seg0 + t];
    __syncthreads();
    for (int stripe = 0; stripe < NSTRIPE; ++stripe) {
        int cs = tails[b * NSTRIPE + stripe];
        size_t base = ((size_t)b * NSTRIPE + stripe) * SUBCAP;
        for (int i = t; i < cs; i += 256) {
            uint2 rec = stage[base + i];
            int pos = atomicAdd(&cur[rec.y - (unsigned)seg0], 1);
            edges[pos] = rec.x;
        }
    }
    __syncthreads();
    if (t < nh) off[seg0 + t] = cur[t];
}

// ---------------- propagation: one wave per segment, 2 edges/iter ----------------
__global__ __launch_bounds__(256) void k_prop(const unsigned* __restrict__ edges,
                                              const int* __restrict__ endo,
                                              const int* __restrict__ cnt,
                                              const ushort* __restrict__ Ecur,
                                              ushort* __restrict__ Enext) {
    int seg  = (blockIdx.x * blockDim.x + threadIdx.x) >> 6;
    int lane = threadIdx.x & 63;
    if (seg >= NSEG) return;
    int end = endo[seg], n = cnt[seg], start = end - n;
    int half = lane >> 5;
    int l31  = lane & 31;

    float ax = 0.0f, ay = 0.0f;
    for (int b = 0; b < n; b += 64) {
        int k = b + lane;
        unsigned pk = (k < n) ? edges[start + k] : 0u;
        int m = min(n - b, 64);
        for (int j = 0; j < m; j += 2) {
            int sel = j + half;
            unsigned pj = __shfl(pk, sel, 64);
            float v = (sel < m) ? __uint_as_float((pj & 0x7FFFu) << 16) : 0.0f;
            unsigned idx = pj >> 15;
            ushort2 ev = ((const ushort2*)(Ecur + (size_t)idx * DIM))[l31];
            ax = fmaf(v, b2f(ev.x), ax);
            ay = fmaf(v, b2f(ev.y), ay);
        }
    }
    ax += __shfl_xor(ax, 32, 64);
    ay += __shfl_xor(ay, 32, 64);
    if (half == 0) {
        ushort2 ec = ((const ushort2*)(Ecur + (size_t)seg * DIM))[l31];
        float zx = ax > 0.0f ? ax : 0.5f * ax;
        float zy = ay > 0.0f ? ay : 0.5f * ay;
        ushort2 o;
        o.x = (ushort)f2b(b2f(ec.x) + zx);
        o.y = (ushort)f2b(b2f(ec.y) + zy);
        ((ushort2*)(Enext + (size_t)seg * DIM))[l31] = o;
    }
}

// ---------------- loss ----------------
__global__ __launch_bounds__(256) void k_loss(const ushort* __restrict__ E0,
                                              const ushort* __restrict__ E1,
                                              const ushort* __restrict__ E2,
                                              const int* __restrict__ uids,
                                              const int* __restrict__ pos,
                                              const int* __restrict__ neg,
                                              float* __restrict__ acc) {
    int wid  = (blockIdx.x * blockDim.x + threadIdx.x) >> 6;
    int lane = threadIdx.x & 63;
    if (wid >= B_USERS) return;

    int uid = uids[wid];
    size_t ub = (size_t)uid * DIM + lane;
    float u = b2f(E0[ub]) + b2f(E1[ub]) + b2f(E2[ub]);

    float pos_min = 1e30f, pos_h = 0.0f;
    for (int p = 0; p < P_POS; ++p) {
        int it = pos[wid * P_POS + p];
        size_t ib = (size_t)(N_U + it) * DIM + lane;
        float si = b2f(E0[ib]) + b2f(E1[ib]) + b2f(E2[ib]);
        float s = u * si;
        #pragma unroll
        for (int o = 32; o > 0; o >>= 1) s += __shfl_xor(s, o, 64);
        pos_min = fminf(pos_min, s);
        pos_h  += fmaxf(1.0f - s, 0.0f);
    }

    float neg_max = -1e30f, neg_h = 0.0f;
    for (int nn = 0; nn < N_NEG; ++nn) {
        int it = neg[wid * N_NEG + nn];
        size_t ib = (size_t)(N_U + it) * DIM + lane;
        float si = b2f(E0[ib]) + b2f(E1[ib]) + b2f(E2[ib]);
        float s = u * si;
        #pragma unroll
        for (int o = 32; o > 0; o >>= 1) s += __shfl_xor(s, o, 64);
        neg_max = fmaxf(neg_max, s);
        neg_h  += fmaxf(s - 0.5f, 0.0f);
    }

    float delta = (neg_max - pos_min > 0.005f) ? 10.0f * (pos_min - neg_max) : 0.0f;
    float contrib = pos_h + (float)P_POS * neg_h + delta * (float)(B_USERS - wid);
    if (lane == 0) atomicAdd(acc, contrib);
}

__global__ void finalize(const float* __restrict__ acc, float* __restrict__ out) {
    out[0] = acc[0] / (float)B_USERS + 0.2f;
}

extern "C" void kernel_launch(void* const* d_in, const int* in_sizes, int n_in,
                              void* d_out, int out_size, void* d_ws, size_t ws_size,
                              hipStream_t stream) {
    const float* Eu0  = (const float*)d_in[0];
    const float* Ei0  = (const float*)d_in[1];
    const float* vals = (const float*)d_in[2];
    const int* rows = (const int*)d_in[7];
    const int* cols = (const int*)d_in[8];
    const int* uids = (const int*)d_in[9];
    const int* pos  = (const int*)d_in[10];
    const int* neg  = (const int*)d_in[11];
    int nnz = in_sizes[2];

    // workspace layout
    unsigned* edges = (unsigned*)d_ws;                               // 2*nnz u32 (16MB)
    uint2*    stage = (uint2*)(edges + (size_t)2 * nnz);             // NBUK*8*SUBCAP uint2 (51MB)
    ushort*   E0b   = (ushort*)(stage + (size_t)NBUK * NSTRIPE * SUBCAP);
    ushort*   E1b   = E0b + (size_t)NSEG * DIM;
    ushort*   E2b   = E1b + (size_t)NSEG * DIM;
    int*      cnt   = (int*)(E2b + (size_t)NSEG * DIM);              // NSEG
    int*      off   = cnt + NSEG;                                    // NSEG
    int*      bsum  = off + NSEG;                                    // 128
    int*      tails = bsum + 128;                                    // NBUK*8
    float*    acc   = (float*)(tails + NBUK * NSTRIPE);

    const int blk = 256;
    const int nb_scan1 = (NSEG + 1023) / 1024;

    hipMemsetAsync(cnt, 0, (size_t)NSEG * sizeof(int), stream);
    hipMemsetAsync(tails, 0, (size_t)NBUK * NSTRIPE * sizeof(int), stream);
    hipMemsetAsync(acc, 0, sizeof(float), stream);

    k_conv<<<(NSEG * (DIM / 2) + blk - 1) / blk, blk, 0, stream>>>(Eu0, Ei0, E0b);
    k_hist<<<(nnz + blk - 1) / blk, blk, 0, stream>>>(rows, cols, cnt, nnz);
    k_scan1<<<nb_scan1, blk, 0, stream>>>(cnt, off, bsum, NSEG);
    k_scan2<<<1, 128, 0, stream>>>(bsum, nb_scan1);
    k_scan3<<<(NSEG + blk - 1) / blk, blk, 0, stream>>>(off, bsum, NSEG);
    k_binA<<<(nnz + blk - 1) / blk, blk, 0, stream>>>(vals, rows, cols, tails, stage, nnz);
    k_binB<<<NBUK, blk, 0, stream>>>(stage, tails, off, edges);

    const int prop_blocks = (NSEG * 64 + blk - 1) / blk;
    k_prop<<<prop_blocks, blk, 0, stream>>>(edges, off, cnt, E0b, E1b);
    k_prop<<<prop_blocks, blk, 0, stream>>>(edges, off, cnt, E1b, E2b);

    k_loss<<<(B_USERS * 64) / blk, blk, 0, stream>>>(E0b, E1b, E2b, uids, pos, neg, acc);
    finalize<<<1, 1, 0, stream>>>(acc, (float*)d_out);
}

// Round 6
// 669.749 us; speedup vs baseline: 2.5683x; 1.0376x over previous
//
#include <hip/hip_runtime.h>

#define N_U   50000
#define N_I   50000
#define NSEG  (N_U + N_I)      // row segments then col segments
#define DIM   64
#define B_USERS 1024
#define P_POS 10
#define N_NEG 40

#define BSEG    128                          // segments per bucket
#define NBUK    ((NSEG + BSEG - 1) / BSEG)   // 782
#define NSTRIPE 8
#define SUBCAP  1024                         // per sub-bucket (mean 640 under balance)
#define OVFCAP  262144                       // spill records (expected 0 used)

// f32 -> bf16 bits (RNE)
__device__ __forceinline__ unsigned f2b(float f) {
    unsigned b = __float_as_uint(f);
    return (b + 0x7FFFu + ((b >> 16) & 1u)) >> 16;
}
__device__ __forceinline__ float b2f(unsigned u) {
    return __uint_as_float(u << 16);
}

// ---- convert Eu0||Ei0 (f32) into one concatenated bf16 table ----
__global__ void k_conv(const float* __restrict__ Eu0, const float* __restrict__ Ei0,
                       ushort* __restrict__ E0b) {
    int p = blockIdx.x * blockDim.x + threadIdx.x;
    if (p >= NSEG * (DIM / 2)) return;
    float2 v = (p < N_U * (DIM / 2)) ? ((const float2*)Eu0)[p]
                                     : ((const float2*)Ei0)[p - N_U * (DIM / 2)];
    ushort2 o;
    o.x = (ushort)f2b(v.x);
    o.y = (ushort)f2b(v.y);
    ((ushort2*)E0b)[p] = o;
}

// ---- phase A: bin edges (4 edges/thread for MLP) + fused histogram ----
// stripe = real XCD id so each sub-bucket's tail lines live in ONE L2.
__global__ __launch_bounds__(256) void k_binA(const float* __restrict__ vals,
                                              const int* __restrict__ rows,
                                              const int* __restrict__ cols,
                                              int* __restrict__ cnt,
                                              int* __restrict__ tails,
                                              uint2* __restrict__ stage,
                                              int* __restrict__ ocnt,
                                              uint2* __restrict__ ovf, int nnz) {
    unsigned xcc;
    asm volatile("s_getreg_b32 %0, hwreg(HW_REG_XCC_ID, 0, 32)" : "=s"(xcc));
    int stripe = (int)(xcc & (NSTRIPE - 1));

    int base = blockIdx.x * 1024 + threadIdx.x;
    bool ok[4]; int r[4], g[4]; unsigned v15[4];
    #pragma unroll
    for (int k = 0; k < 4; ++k) {
        int e = base + k * 256;
        ok[k] = e < nnz;
        int ee = ok[k] ? e : 0;
        r[k] = rows[ee];
        g[k] = N_U + cols[ee];
        unsigned b = __float_as_uint(vals[ee]);
        v15[k] = ((b + 0x7FFFu + ((b >> 16) & 1u)) >> 16) & 0x7FFFu;
    }
    // histogram: no return value -> fire-and-forget atomics
    #pragma unroll
    for (int k = 0; k < 4; ++k) {
        if (ok[k]) { atomicAdd(&cnt[r[k]], 1); atomicAdd(&cnt[g[k]], 1); }
    }
    // reserve slots (independent -> pipelined)
    int s1[4], s2[4];
    #pragma unroll
    for (int k = 0; k < 4; ++k) {
        if (ok[k]) {
            s1[k] = atomicAdd(&tails[(r[k] >> 7) * NSTRIPE + stripe], 1);
            s2[k] = atomicAdd(&tails[(g[k] >> 7) * NSTRIPE + stripe], 1);
        }
    }
    // stores
    #pragma unroll
    for (int k = 0; k < 4; ++k) {
        if (!ok[k]) continue;
        uint2 rec1; rec1.x = (((unsigned)g[k]) << 15) | v15[k]; rec1.y = (unsigned)r[k];
        if (s1[k] < SUBCAP)
            stage[((size_t)(r[k] >> 7) * NSTRIPE + stripe) * SUBCAP + s1[k]] = rec1;
        else { int o = atomicAdd(ocnt, 1); if (o < OVFCAP) ovf[o] = rec1; }
        uint2 rec2; rec2.x = (((unsigned)r[k]) << 15) | v15[k]; rec2.y = (unsigned)g[k];
        if (s2[k] < SUBCAP)
            stage[((size_t)(g[k] >> 7) * NSTRIPE + stripe) * SUBCAP + s2[k]] = rec2;
        else { int o = atomicAdd(ocnt, 1); if (o < OVFCAP) ovf[o] = rec2; }
    }
}

// ---------------- scans (exclusive prefix over cnt -> off) ----------------
__global__ __launch_bounds__(256) void k_scan1(const int* __restrict__ cnt,
                                               int* __restrict__ off,
                                               int* __restrict__ bsum, int n) {
    __shared__ int sh[256];
    int b = blockIdx.x, t = threadIdx.x;
    int base = b * 1024 + t * 4;
    int v0 = (base + 0 < n) ? cnt[base + 0] : 0;
    int v1 = (base + 1 < n) ? cnt[base + 1] : 0;
    int v2 = (base + 2 < n) ? cnt[base + 2] : 0;
    int v3 = (base + 3 < n) ? cnt[base + 3] : 0;
    int tsum = v0 + v1 + v2 + v3;
    sh[t] = tsum;
    __syncthreads();
    for (int o = 1; o < 256; o <<= 1) {
        int x = (t >= o) ? sh[t - o] : 0;
        __syncthreads();
        sh[t] += x;
        __syncthreads();
    }
    int excl = sh[t] - tsum;
    if (t == 255) bsum[b] = sh[255];
    if (base + 0 < n) off[base + 0] = excl;
    if (base + 1 < n) off[base + 1] = excl + v0;
    if (base + 2 < n) off[base + 2] = excl + v0 + v1;
    if (base + 3 < n) off[base + 3] = excl + v0 + v1 + v2;
}

__global__ void k_scan2(int* bsum, int nb) {
    __shared__ int sh[128];
    int t = threadIdx.x;
    int v = (t < nb) ? bsum[t] : 0;
    sh[t] = v;
    __syncthreads();
    for (int o = 1; o < 128; o <<= 1) {
        int x = (t >= o) ? sh[t - o] : 0;
        __syncthreads();
        sh[t] += x;
        __syncthreads();
    }
    if (t < nb) bsum[t] = sh[t] - v;
}

__global__ void k_scan3(int* __restrict__ off, const int* __restrict__ bsum, int n) {
    int i = blockIdx.x * blockDim.x + threadIdx.x;
    if (i < n) off[i] += bsum[i >> 10];
}

// ---- phase B: per bucket, place staged records at final CSR positions ----
// off[] holds segment starts on entry, segment ENDs on exit
__global__ __launch_bounds__(256) void k_binB(const uint2* __restrict__ stage,
                                              const int* __restrict__ tails,
                                              int* __restrict__ off,
                                              unsigned* __restrict__ edges) {
    int b = blockIdx.x;
    int t = threadIdx.x;
    __shared__ int cur[BSEG];
    int seg0 = b * BSEG;
    int nh = min(BSEG, NSEG - seg0);
    if (t < nh) cur[t] = off[seg0 + t];
    __syncthreads();
    for (int stripe = 0; stripe < NSTRIPE; ++stripe) {
        int cs = min(tails[b * NSTRIPE + stripe], SUBCAP);
        size_t base = ((size_t)b * NSTRIPE + stripe) * SUBCAP;
        for (int i = t; i < cs; i += 256) {
            uint2 rec = stage[base + i];
            int pos = atomicAdd(&cur[rec.y - (unsigned)seg0], 1);
            edges[pos] = rec.x;
        }
    }
    __syncthreads();
    if (t < nh) off[seg0 + t] = cur[t];
}

// ---- place spilled records (expected none) ----
__global__ void k_ovf(const int* __restrict__ ocnt, const uint2* __restrict__ ovf,
                      int* __restrict__ off, unsigned* __restrict__ edges) {
    int n = min(ocnt[0], OVFCAP);
    for (int i = threadIdx.x; i < n; i += 256) {
        uint2 rec = ovf[i];
        int pos = atomicAdd(&off[rec.y], 1);
        edges[pos] = rec.x;
    }
}

// ---------------- propagation: one wave per segment, 2 edges/iter ----------------
__global__ __launch_bounds__(256) void k_prop(const unsigned* __restrict__ edges,
                                              const int* __restrict__ endo,
                                              const int* __restrict__ cnt,
                                              const ushort* __restrict__ Ecur,
                                              ushort* __restrict__ Enext) {
    int seg  = (blockIdx.x * blockDim.x + threadIdx.x) >> 6;
    int lane = threadIdx.x & 63;
    if (seg >= NSEG) return;
    int end = endo[seg], n = cnt[seg], start = end - n;
    int half = lane >> 5;
    int l31  = lane & 31;

    float ax = 0.0f, ay = 0.0f;
    for (int b = 0; b < n; b += 64) {
        int k = b + lane;
        unsigned pk = (k < n) ? edges[start + k] : 0u;
        int m = min(n - b, 64);
        for (int j = 0; j < m; j += 2) {
            int sel = j + half;
            unsigned pj = __shfl(pk, sel, 64);
            float v = (sel < m) ? __uint_as_float((pj & 0x7FFFu) << 16) : 0.0f;
            unsigned idx = pj >> 15;
            ushort2 ev = ((const ushort2*)(Ecur + (size_t)idx * DIM))[l31];
            ax = fmaf(v, b2f(ev.x), ax);
            ay = fmaf(v, b2f(ev.y), ay);
        }
    }
    ax += __shfl_xor(ax, 32, 64);
    ay += __shfl_xor(ay, 32, 64);
    if (half == 0) {
        ushort2 ec = ((const ushort2*)(Ecur + (size_t)seg * DIM))[l31];
        float zx = ax > 0.0f ? ax : 0.5f * ax;
        float zy = ay > 0.0f ? ay : 0.5f * ay;
        ushort2 o;
        o.x = (ushort)f2b(b2f(ec.x) + zx);
        o.y = (ushort)f2b(b2f(ec.y) + zy);
        ((ushort2*)(Enext + (size_t)seg * DIM))[l31] = o;
    }
}

// ---------------- loss ----------------
__global__ __launch_bounds__(256) void k_loss(const ushort* __restrict__ E0,
                                              const ushort* __restrict__ E1,
                                              const ushort* __restrict__ E2,
                                              const int* __restrict__ uids,
                                              const int* __restrict__ pos,
                                              const int* __restrict__ neg,
                                              float* __restrict__ acc) {
    int wid  = (blockIdx.x * blockDim.x + threadIdx.x) >> 6;
    int lane = threadIdx.x & 63;
    if (wid >= B_USERS) return;

    int uid = uids[wid];
    size_t ub = (size_t)uid * DIM + lane;
    float u = b2f(E0[ub]) + b2f(E1[ub]) + b2f(E2[ub]);

    float pos_min = 1e30f, pos_h = 0.0f;
    for (int p = 0; p < P_POS; ++p) {
        int it = pos[wid * P_POS + p];
        size_t ib = (size_t)(N_U + it) * DIM + lane;
        float si = b2f(E0[ib]) + b2f(E1[ib]) + b2f(E2[ib]);
        float s = u * si;
        #pragma unroll
        for (int o = 32; o > 0; o >>= 1) s += __shfl_xor(s, o, 64);
        pos_min = fminf(pos_min, s);
        pos_h  += fmaxf(1.0f - s, 0.0f);
    }

    float neg_max = -1e30f, neg_h = 0.0f;
    for (int nn = 0; nn < N_NEG; ++nn) {
        int it = neg[wid * N_NEG + nn];
        size_t ib = (size_t)(N_U + it) * DIM + lane;
        float si = b2f(E0[ib]) + b2f(E1[ib]) + b2f(E2[ib]);
        float s = u * si;
        #pragma unroll
        for (int o = 32; o > 0; o >>= 1) s += __shfl_xor(s, o, 64);
        neg_max = fmaxf(neg_max, s);
        neg_h  += fmaxf(s - 0.5f, 0.0f);
    }

    float delta = (neg_max - pos_min > 0.005f) ? 10.0f * (pos_min - neg_max) : 0.0f;
    float contrib = pos_h + (float)P_POS * neg_h + delta * (float)(B_USERS - wid);
    if (lane == 0) atomicAdd(acc, contrib);
}

__global__ void finalize(const float* __restrict__ acc, float* __restrict__ out) {
    out[0] = acc[0] / (float)B_USERS + 0.2f;
}

extern "C" void kernel_launch(void* const* d_in, const int* in_sizes, int n_in,
                              void* d_out, int out_size, void* d_ws, size_t ws_size,
                              hipStream_t stream) {
    const float* Eu0  = (const float*)d_in[0];
    const float* Ei0  = (const float*)d_in[1];
    const float* vals = (const float*)d_in[2];
    const int* rows = (const int*)d_in[7];
    const int* cols = (const int*)d_in[8];
    const int* uids = (const int*)d_in[9];
    const int* pos  = (const int*)d_in[10];
    const int* neg  = (const int*)d_in[11];
    int nnz = in_sizes[2];

    // workspace layout
    unsigned* edges = (unsigned*)d_ws;                               // 2*nnz u32
    uint2*    stage = (uint2*)(edges + (size_t)2 * nnz);             // NBUK*8*SUBCAP uint2
    uint2*    ovf   = stage + (size_t)NBUK * NSTRIPE * SUBCAP;       // OVFCAP uint2
    ushort*   E0b   = (ushort*)(ovf + OVFCAP);                       // NSEG*DIM bf16 x3
    ushort*   E1b   = E0b + (size_t)NSEG * DIM;
    ushort*   E2b   = E1b + (size_t)NSEG * DIM;
    // zeroed region: cnt, tails, ocnt, acc (contiguous -> one memset)
    int*      cnt   = (int*)(E2b + (size_t)NSEG * DIM);              // NSEG
    int*      tails = cnt + NSEG;                                    // NBUK*8
    int*      ocnt  = tails + NBUK * NSTRIPE;                        // 1
    float*    acc   = (float*)(ocnt + 1);                            // 1
    int*      off   = (int*)(acc + 1);                               // NSEG (scan-written)
    int*      bsum  = off + NSEG;                                    // 128

    const int blk = 256;
    const int nb_scan1 = (NSEG + 1023) / 1024;
    const size_t zero_ints = (size_t)NSEG + NBUK * NSTRIPE + 2;

    hipMemsetAsync(cnt, 0, zero_ints * sizeof(int), stream);

    k_conv<<<(NSEG * (DIM / 2) + blk - 1) / blk, blk, 0, stream>>>(Eu0, Ei0, E0b);
    k_binA<<<(nnz + 1023) / 1024, blk, 0, stream>>>(vals, rows, cols, cnt, tails,
                                                    stage, ocnt, ovf, nnz);
    k_scan1<<<nb_scan1, blk, 0, stream>>>(cnt, off, bsum, NSEG);
    k_scan2<<<1, 128, 0, stream>>>(bsum, nb_scan1);
    k_scan3<<<(NSEG + blk - 1) / blk, blk, 0, stream>>>(off, bsum, NSEG);
    k_binB<<<NBUK, blk, 0, stream>>>(stage, tails, off, edges);
    k_ovf<<<1, blk, 0, stream>>>(ocnt, ovf, off, edges);

    const int prop_blocks = (NSEG * 64 + blk - 1) / blk;
    k_prop<<<prop_blocks, blk, 0, stream>>>(edges, off, cnt, E0b, E1b);
    k_prop<<<prop_blocks, blk, 0, stream>>>(edges, off, cnt, E1b, E2b);

    k_loss<<<(B_USERS * 64) / blk, blk, 0, stream>>>(E0b, E1b, E2b, uids, pos, neg, acc);
    finalize<<<1, 1, 0, stream>>>(acc, (float*)d_out);
}

// Round 9
// 374.572 us; speedup vs baseline: 4.5923x; 1.7880x over previous
//
#include <hip/hip_runtime.h>

#define N_U   50000
#define N_I   50000
#define NSEG  (N_U + N_I)      // row segments then col segments
#define DIM   64
#define B_USERS 1024
#define P_POS 10
#define N_NEG 40

#define BSEG  128                          // segments per bucket
#define NBUK  782                          // ceil(NSEG/BSEG)
#define CAP   8192                         // staging capacity per bucket (mean 5115, +40 sigma)
#define EPB   4096                         // edges per binA2 block (512 thr x 8)

// f32 -> bf16 bits (RNE)
__device__ __forceinline__ unsigned f2b(float f) {
    unsigned b = __float_as_uint(f);
    return (b + 0x7FFFu + ((b >> 16) & 1u)) >> 16;
}
__device__ __forceinline__ float b2f(unsigned u) {
    return __uint_as_float(u << 16);
}

// ---- convert Eu0||Ei0 (f32) into one concatenated bf16 table ----
__global__ void k_conv(const float* __restrict__ Eu0, const float* __restrict__ Ei0,
                       ushort* __restrict__ E0b) {
    int p = blockIdx.x * blockDim.x + threadIdx.x;
    if (p >= NSEG * (DIM / 2)) return;
    float2 v = (p < N_U * (DIM / 2)) ? ((const float2*)Eu0)[p]
                                     : ((const float2*)Ei0)[p - N_U * (DIM / 2)];
    ushort2 o;
    o.x = (ushort)f2b(v.x);
    o.y = (ushort)f2b(v.y);
    ((ushort2*)E0b)[p] = o;
}

// ---- binA2: bucket-append via LDS ranks + one fat global atomic per (block,bucket) ----
// record: x = nbr<<15 | val15 ; y = local segment (seg & 127)
__global__ __launch_bounds__(512) void k_binA2(const float* __restrict__ vals,
                                               const int* __restrict__ rows,
                                               const int* __restrict__ cols,
                                               int* __restrict__ tails,
                                               uint2* __restrict__ stage, int nnz) {
    __shared__ int hist[NBUK];
    __shared__ int base[NBUK];
    int t = threadIdx.x;
    for (int i = t; i < NBUK; i += 512) hist[i] = 0;
    __syncthreads();

    unsigned recx[16];
    unsigned meta[16];   // bucket<<20 | rank<<7 | lseg   (rank < 8192 fits 13 bits)
    int e0 = blockIdx.x * EPB;
    #pragma unroll
    for (int k = 0; k < 8; ++k) {
        int e = e0 + k * 512 + t;
        bool ok = e < nnz;
        int ee = ok ? e : 0;
        int r = rows[ee];
        int g = N_U + cols[ee];
        unsigned b = __float_as_uint(vals[ee]);
        unsigned v15 = ((b + 0x7FFFu + ((b >> 16) & 1u)) >> 16) & 0x7FFFu;
        if (ok) {
            int b0 = r >> 7;
            int rk0 = atomicAdd(&hist[b0], 1);
            recx[2 * k]     = (((unsigned)g) << 15) | v15;
            meta[2 * k]     = ((unsigned)b0 << 20) | ((unsigned)rk0 << 7) | (unsigned)(r & 127);
            int b1 = g >> 7;
            int rk1 = atomicAdd(&hist[b1], 1);
            recx[2 * k + 1] = (((unsigned)r) << 15) | v15;
            meta[2 * k + 1] = ((unsigned)b1 << 20) | ((unsigned)rk1 << 7) | (unsigned)(g & 127);
        } else {
            meta[2 * k] = 0xFFFFFFFFu;
            meta[2 * k + 1] = 0xFFFFFFFFu;
        }
    }
    __syncthreads();
    for (int i = t; i < NBUK; i += 512) {
        int h = hist[i];
        base[i] = h ? atomicAdd(&tails[i], h) : 0;
    }
    __syncthreads();
    #pragma unroll
    for (int k = 0; k < 16; ++k) {
        unsigned m = meta[k];
        if (m == 0xFFFFFFFFu) continue;
        int bkt  = m >> 20;
        int rank = (m >> 7) & 0x1FFF;
        int slot = base[bkt] + rank;
        if (slot < CAP) {
            uint2 rec;
            rec.x = recx[k];
            rec.y = m & 127u;
            stage[((size_t)bkt << 13) + slot] = rec;
        }
    }
}

// ---- exclusive scan of 782 bucket totals (single block) ----
__global__ __launch_bounds__(1024) void k_bscan(const int* __restrict__ tails,
                                                int* __restrict__ bukoff) {
    __shared__ int sh[1024];
    int t = threadIdx.x;
    int v = (t < NBUK) ? min(tails[t], CAP) : 0;
    sh[t] = v;
    __syncthreads();
    for (int o = 1; o < 1024; o <<= 1) {
        int x = (t >= o) ? sh[t - o] : 0;
        __syncthreads();
        sh[t] += x;
        __syncthreads();
    }
    if (t < NBUK) bukoff[t] = sh[t] - v;
}

// ---- binB2: per bucket, LDS 128-hist + scan, write cnt/endo, place edges ----
__global__ __launch_bounds__(256) void k_binB2(const uint2* __restrict__ stage,
                                               const int* __restrict__ tails,
                                               const int* __restrict__ bukoff,
                                               unsigned* __restrict__ edges,
                                               int* __restrict__ cnt,
                                               int* __restrict__ endo) {
    __shared__ int h[BSEG];
    __shared__ int sc[BSEG];
    __shared__ int cur[BSEG];
    int b = blockIdx.x, t = threadIdx.x;
    int cs = min(tails[b], CAP);
    size_t sbase = (size_t)b << 13;
    if (t < BSEG) h[t] = 0;
    __syncthreads();
    for (int i = t; i < cs; i += 256)
        atomicAdd(&h[stage[sbase + i].y], 1);
    __syncthreads();
    if (t < BSEG) sc[t] = h[t];
    __syncthreads();
    for (int o = 1; o < BSEG; o <<= 1) {
        int x = (t < BSEG && t >= o) ? sc[t - o] : 0;
        __syncthreads();
        if (t < BSEG) sc[t] += x;
        __syncthreads();
    }
    int seg0 = b * BSEG;
    if (t < BSEG) {
        int start = bukoff[b] + sc[t] - h[t];
        cur[t] = start;
        int seg = seg0 + t;
        if (seg < NSEG) { cnt[seg] = h[t]; endo[seg] = start + h[t]; }
    }
    __syncthreads();
    for (int i = t; i < cs; i += 256) {
        uint2 rec = stage[sbase + i];
        int pos = atomicAdd(&cur[rec.y], 1);
        edges[pos] = rec.x;
    }
}

// ---------------- propagation: one wave per segment, 2 edges/iter ----------------
__global__ __launch_bounds__(256) void k_prop(const unsigned* __restrict__ edges,
                                              const int* __restrict__ endo,
                                              const int* __restrict__ cnt,
                                              const ushort* __restrict__ Ecur,
                                              ushort* __restrict__ Enext) {
    int seg  = (blockIdx.x * blockDim.x + threadIdx.x) >> 6;
    int lane = threadIdx.x & 63;
    if (seg >= NSEG) return;
    int end = endo[seg], n = cnt[seg], start = end - n;
    int half = lane >> 5;
    int l31  = lane & 31;

    float ax = 0.0f, ay = 0.0f;
    for (int b = 0; b < n; b += 64) {
        int k = b + lane;
        unsigned pk = (k < n) ? edges[start + k] : 0u;
        int m = min(n - b, 64);
        for (int j = 0; j < m; j += 2) {
            int sel = j + half;
            unsigned pj = __shfl(pk, sel, 64);
            float v = (sel < m) ? __uint_as_float((pj & 0x7FFFu) << 16) : 0.0f;
            unsigned idx = pj >> 15;
            ushort2 ev = ((const ushort2*)(Ecur + (size_t)idx * DIM))[l31];
            ax = fmaf(v, b2f(ev.x), ax);
            ay = fmaf(v, b2f(ev.y), ay);
        }
    }
    ax += __shfl_xor(ax, 32, 64);
    ay += __shfl_xor(ay, 32, 64);
    if (half == 0) {
        ushort2 ec = ((const ushort2*)(Ecur + (size_t)seg * DIM))[l31];
        float zx = ax > 0.0f ? ax : 0.5f * ax;
        float zy = ay > 0.0f ? ay : 0.5f * ay;
        ushort2 o;
        o.x = (ushort)f2b(b2f(ec.x) + zx);
        o.y = (ushort)f2b(b2f(ec.y) + zy);
        ((ushort2*)(Enext + (size_t)seg * DIM))[l31] = o;
    }
}

// ---------------- loss ----------------
__global__ __launch_bounds__(256) void k_loss(const ushort* __restrict__ E0,
                                              const ushort* __restrict__ E1,
                                              const ushort* __restrict__ E2,
                                              const int* __restrict__ uids,
                                              const int* __restrict__ pos,
                                              const int* __restrict__ neg,
                                              float* __restrict__ acc) {
    int wid  = (blockIdx.x * blockDim.x + threadIdx.x) >> 6;
    int lane = threadIdx.x & 63;
    if (wid >= B_USERS) return;

    int uid = uids[wid];
    size_t ub = (size_t)uid * DIM + lane;
    float u = b2f(E0[ub]) + b2f(E1[ub]) + b2f(E2[ub]);

    float pos_min = 1e30f, pos_h = 0.0f;
    for (int p = 0; p < P_POS; ++p) {
        int it = pos[wid * P_POS + p];
        size_t ib = (size_t)(N_U + it) * DIM + lane;
        float si = b2f(E0[ib]) + b2f(E1[ib]) + b2f(E2[ib]);
        float s = u * si;
        #pragma unroll
        for (int o = 32; o > 0; o >>= 1) s += __shfl_xor(s, o, 64);
        pos_min = fminf(pos_min, s);
        pos_h  += fmaxf(1.0f - s, 0.0f);
    }

    float neg_max = -1e30f, neg_h = 0.0f;
    for (int nn = 0; nn < N_NEG; ++nn) {
        int it = neg[wid * N_NEG + nn];
        size_t ib = (size_t)(N_U + it) * DIM + lane;
        float si = b2f(E0[ib]) + b2f(E1[ib]) + b2f(E2[ib]);
        float s = u * si;
        #pragma unroll
        for (int o = 32; o > 0; o >>= 1) s += __shfl_xor(s, o, 64);
        neg_max = fmaxf(neg_max, s);
        neg_h  += fmaxf(s - 0.5f, 0.0f);
    }

    float delta = (neg_max - pos_min > 0.005f) ? 10.0f * (pos_min - neg_max) : 0.0f;
    float contrib = pos_h + (float)P_POS * neg_h + delta * (float)(B_USERS - wid);
    if (lane == 0) atomicAdd(acc, contrib);
}

__global__ void finalize(const float* __restrict__ acc, float* __restrict__ out) {
    out[0] = acc[0] / (float)B_USERS + 0.2f;
}

extern "C" void kernel_launch(void* const* d_in, const int* in_sizes, int n_in,
                              void* d_out, int out_size, void* d_ws, size_t ws_size,
                              hipStream_t stream) {
    const float* Eu0  = (const float*)d_in[0];
    const float* Ei0  = (const float*)d_in[1];
    const float* vals = (const float*)d_in[2];
    const int* rows = (const int*)d_in[7];
    const int* cols = (const int*)d_in[8];
    const int* uids = (const int*)d_in[9];
    const int* pos  = (const int*)d_in[10];
    const int* neg  = (const int*)d_in[11];
    int nnz = in_sizes[2];

    // workspace layout
    unsigned* edges  = (unsigned*)d_ws;                         // 2*nnz u32 (16MB)
    uint2*    stage  = (uint2*)(edges + (size_t)2 * nnz);       // NBUK*CAP uint2 (51MB)
    ushort*   E0b    = (ushort*)(stage + (size_t)NBUK * CAP);   // 3x NSEG*DIM bf16
    ushort*   E1b    = E0b + (size_t)NSEG * DIM;
    ushort*   E2b    = E1b + (size_t)NSEG * DIM;
    int*      cnt    = (int*)(E2b + (size_t)NSEG * DIM);        // NSEG
    int*      endo   = cnt + NSEG;                              // NSEG
    int*      bukoff = endo + NSEG;                             // NBUK
    int*      tails  = bukoff + NBUK;                           // NBUK   (zeroed)
    float*    acc    = (float*)(tails + NBUK);                  // 1      (zeroed)

    const int blk = 256;

    hipMemsetAsync(tails, 0, (NBUK + 1) * sizeof(int), stream);

    k_conv<<<(NSEG * (DIM / 2) + blk - 1) / blk, blk, 0, stream>>>(Eu0, Ei0, E0b);
    k_binA2<<<(nnz + EPB - 1) / EPB, 512, 0, stream>>>(vals, rows, cols, tails, stage, nnz);
    k_bscan<<<1, 1024, 0, stream>>>(tails, bukoff);
    k_binB2<<<NBUK, blk, 0, stream>>>(stage, tails, bukoff, edges, cnt, endo);

    const int prop_blocks = (NSEG * 64 + blk - 1) / blk;
    k_prop<<<prop_blocks, blk, 0, stream>>>(edges, endo, cnt, E0b, E1b);
    k_prop<<<prop_blocks, blk, 0, stream>>>(edges, endo, cnt, E1b, E2b);

    k_loss<<<(B_USERS * 64) / blk, blk, 0, stream>>>(E0b, E1b, E2b, uids, pos, neg, acc);
    finalize<<<1, 1, 0, stream>>>(acc, (float*)d_out);
}

// Round 10
// 297.999 us; speedup vs baseline: 5.7723x; 1.2570x over previous
//
#include <hip/hip_runtime.h>

#define N_U   50000
#define N_I   50000
#define NSEG  (N_U + N_I)      // row segments then col segments
#define DIM   64
#define B_USERS 1024
#define P_POS 10
#define N_NEG 40

#define BSEG  128                          // segments per bucket
#define NBUK  782                          // ceil(NSEG/BSEG)
#define CAP   8192                         // staging capacity per bucket (mean 5115, +40 sigma)
#define EPB   4096                         // edges per binA2 block (512 thr x 8)

// f32 -> bf16 bits (RNE)
__device__ __forceinline__ unsigned f2b(float f) {
    unsigned b = __float_as_uint(f);
    return (b + 0x7FFFu + ((b >> 16) & 1u)) >> 16;
}
__device__ __forceinline__ float b2f(unsigned u) {
    return __uint_as_float(u << 16);
}

// ---- convert Eu0||Ei0 (f32) into one concatenated bf16 table ----
__global__ void k_conv(const float* __restrict__ Eu0, const float* __restrict__ Ei0,
                       ushort* __restrict__ E0b) {
    int p = blockIdx.x * blockDim.x + threadIdx.x;
    if (p >= NSEG * (DIM / 2)) return;
    float2 v = (p < N_U * (DIM / 2)) ? ((const float2*)Eu0)[p]
                                     : ((const float2*)Ei0)[p - N_U * (DIM / 2)];
    ushort2 o;
    o.x = (ushort)f2b(v.x);
    o.y = (ushort)f2b(v.y);
    ((ushort2*)E0b)[p] = o;
}

// ---- binA2: bucket-append via LDS ranks + one fat global atomic per (block,bucket) ----
// record: x = nbr<<15 | val15 ; y = local segment (seg & 127)
__global__ __launch_bounds__(512) void k_binA2(const float* __restrict__ vals,
                                               const int* __restrict__ rows,
                                               const int* __restrict__ cols,
                                               int* __restrict__ tails,
                                               uint2* __restrict__ stage, int nnz) {
    __shared__ int hist[NBUK];
    __shared__ int base[NBUK];
    int t = threadIdx.x;
    for (int i = t; i < NBUK; i += 512) hist[i] = 0;
    __syncthreads();

    unsigned recx[16];
    unsigned meta[16];   // bucket<<20 | rank<<7 | lseg   (rank < 8192 fits 13 bits)
    int e0 = blockIdx.x * EPB;
    #pragma unroll
    for (int k = 0; k < 8; ++k) {
        int e = e0 + k * 512 + t;
        bool ok = e < nnz;
        int ee = ok ? e : 0;
        int r = rows[ee];
        int g = N_U + cols[ee];
        unsigned b = __float_as_uint(vals[ee]);
        unsigned v15 = ((b + 0x7FFFu + ((b >> 16) & 1u)) >> 16) & 0x7FFFu;
        if (ok) {
            int b0 = r >> 7;
            int rk0 = atomicAdd(&hist[b0], 1);
            recx[2 * k]     = (((unsigned)g) << 15) | v15;
            meta[2 * k]     = ((unsigned)b0 << 20) | ((unsigned)rk0 << 7) | (unsigned)(r & 127);
            int b1 = g >> 7;
            int rk1 = atomicAdd(&hist[b1], 1);
            recx[2 * k + 1] = (((unsigned)r) << 15) | v15;
            meta[2 * k + 1] = ((unsigned)b1 << 20) | ((unsigned)rk1 << 7) | (unsigned)(g & 127);
        } else {
            meta[2 * k] = 0xFFFFFFFFu;
            meta[2 * k + 1] = 0xFFFFFFFFu;
        }
    }
    __syncthreads();
    for (int i = t; i < NBUK; i += 512) {
        int h = hist[i];
        base[i] = h ? atomicAdd(&tails[i], h) : 0;
    }
    __syncthreads();
    #pragma unroll
    for (int k = 0; k < 16; ++k) {
        unsigned m = meta[k];
        if (m == 0xFFFFFFFFu) continue;
        int bkt  = m >> 20;
        int rank = (m >> 7) & 0x1FFF;
        int slot = base[bkt] + rank;
        if (slot < CAP) {
            uint2 rec;
            rec.x = recx[k];
            rec.y = m & 127u;
            stage[((size_t)bkt << 13) + slot] = rec;
        }
    }
}

// ---- exclusive scan of 782 bucket totals (single block) ----
__global__ __launch_bounds__(1024) void k_bscan(const int* __restrict__ tails,
                                                int* __restrict__ bukoff) {
    __shared__ int sh[1024];
    int t = threadIdx.x;
    int v = (t < NBUK) ? min(tails[t], CAP) : 0;
    sh[t] = v;
    __syncthreads();
    for (int o = 1; o < 1024; o <<= 1) {
        int x = (t >= o) ? sh[t - o] : 0;
        __syncthreads();
        sh[t] += x;
        __syncthreads();
    }
    if (t < NBUK) bukoff[t] = sh[t] - v;
}

// ---- binB2: per bucket, LDS 128-hist + scan, write cnt/endo, place edges ----
__global__ __launch_bounds__(256) void k_binB2(const uint2* __restrict__ stage,
                                               const int* __restrict__ tails,
                                               const int* __restrict__ bukoff,
                                               unsigned* __restrict__ edges,
                                               int* __restrict__ cnt,
                                               int* __restrict__ endo) {
    __shared__ int h[BSEG];
    __shared__ int sc[BSEG];
    __shared__ int cur[BSEG];
    int b = blockIdx.x, t = threadIdx.x;
    int cs = min(tails[b], CAP);
    size_t sbase = (size_t)b << 13;
    if (t < BSEG) h[t] = 0;
    __syncthreads();
    for (int i = t; i < cs; i += 256)
        atomicAdd(&h[stage[sbase + i].y], 1);
    __syncthreads();
    if (t < BSEG) sc[t] = h[t];
    __syncthreads();
    for (int o = 1; o < BSEG; o <<= 1) {
        int x = (t < BSEG && t >= o) ? sc[t - o] : 0;
        __syncthreads();
        if (t < BSEG) sc[t] += x;
        __syncthreads();
    }
    int seg0 = b * BSEG;
    if (t < BSEG) {
        int start = bukoff[b] + sc[t] - h[t];
        cur[t] = start;
        int seg = seg0 + t;
        if (seg < NSEG) { cnt[seg] = h[t]; endo[seg] = start + h[t]; }
    }
    __syncthreads();
    for (int i = t; i < cs; i += 256) {
        uint2 rec = stage[sbase + i];
        int pos = atomicAdd(&cur[rec.y], 1);
        edges[pos] = rec.x;
    }
}

// ---------------- propagation: one wave per segment, 4 edges/iter ----------------
// 16-lane groups: group q handles edge j+q; lane l15 loads ushort4 = dims 4*l15..4*l15+3
__global__ __launch_bounds__(256) void k_prop(const unsigned* __restrict__ edges,
                                              const int* __restrict__ endo,
                                              const int* __restrict__ cnt,
                                              const ushort* __restrict__ Ecur,
                                              ushort* __restrict__ Enext) {
    int seg  = (blockIdx.x * blockDim.x + threadIdx.x) >> 6;
    int lane = threadIdx.x & 63;
    if (seg >= NSEG) return;
    int end = endo[seg], n = cnt[seg], start = end - n;
    int q   = lane >> 4;    // quarter 0..3
    int l15 = lane & 15;

    float a0 = 0.0f, a1 = 0.0f, a2 = 0.0f, a3 = 0.0f;
    for (int b = 0; b < n; b += 64) {
        int k = b + lane;
        unsigned pk = (k < n) ? edges[start + k] : 0u;
        int m = min(n - b, 64);
        for (int j = 0; j < m; j += 4) {
            int sel = j + q;
            unsigned pj = __shfl(pk, sel, 64);
            float v = (sel < m) ? __uint_as_float((pj & 0x7FFFu) << 16) : 0.0f;
            unsigned idx = pj >> 15;
            ushort4 ev = ((const ushort4*)(Ecur + (size_t)idx * DIM))[l15];
            a0 = fmaf(v, b2f(ev.x), a0);
            a1 = fmaf(v, b2f(ev.y), a1);
            a2 = fmaf(v, b2f(ev.z), a2);
            a3 = fmaf(v, b2f(ev.w), a3);
        }
    }
    // reduce across the 4 quarters (lane bits 4 and 5)
    a0 += __shfl_xor(a0, 16, 64); a1 += __shfl_xor(a1, 16, 64);
    a2 += __shfl_xor(a2, 16, 64); a3 += __shfl_xor(a3, 16, 64);
    a0 += __shfl_xor(a0, 32, 64); a1 += __shfl_xor(a1, 32, 64);
    a2 += __shfl_xor(a2, 32, 64); a3 += __shfl_xor(a3, 32, 64);
    if (q == 0) {
        ushort4 ec = ((const ushort4*)(Ecur + (size_t)seg * DIM))[l15];
        float z0 = a0 > 0.0f ? a0 : 0.5f * a0;
        float z1 = a1 > 0.0f ? a1 : 0.5f * a1;
        float z2 = a2 > 0.0f ? a2 : 0.5f * a2;
        float z3 = a3 > 0.0f ? a3 : 0.5f * a3;
        ushort4 o;
        o.x = (ushort)f2b(b2f(ec.x) + z0);
        o.y = (ushort)f2b(b2f(ec.y) + z1);
        o.z = (ushort)f2b(b2f(ec.z) + z2);
        o.w = (ushort)f2b(b2f(ec.w) + z3);
        ((ushort4*)(Enext + (size_t)seg * DIM))[l15] = o;
    }
}

// ---------------- loss ----------------
__global__ __launch_bounds__(256) void k_loss(const ushort* __restrict__ E0,
                                              const ushort* __restrict__ E1,
                                              const ushort* __restrict__ E2,
                                              const int* __restrict__ uids,
                                              const int* __restrict__ pos,
                                              const int* __restrict__ neg,
                                              float* __restrict__ acc) {
    int wid  = (blockIdx.x * blockDim.x + threadIdx.x) >> 6;
    int lane = threadIdx.x & 63;
    if (wid >= B_USERS) return;

    int uid = uids[wid];
    size_t ub = (size_t)uid * DIM + lane;
    float u = b2f(E0[ub]) + b2f(E1[ub]) + b2f(E2[ub]);

    float pos_min = 1e30f, pos_h = 0.0f;
    for (int p = 0; p < P_POS; ++p) {
        int it = pos[wid * P_POS + p];
        size_t ib = (size_t)(N_U + it) * DIM + lane;
        float si = b2f(E0[ib]) + b2f(E1[ib]) + b2f(E2[ib]);
        float s = u * si;
        #pragma unroll
        for (int o = 32; o > 0; o >>= 1) s += __shfl_xor(s, o, 64);
        pos_min = fminf(pos_min, s);
        pos_h  += fmaxf(1.0f - s, 0.0f);
    }

    float neg_max = -1e30f, neg_h = 0.0f;
    for (int nn = 0; nn < N_NEG; ++nn) {
        int it = neg[wid * N_NEG + nn];
        size_t ib = (size_t)(N_U + it) * DIM + lane;
        float si = b2f(E0[ib]) + b2f(E1[ib]) + b2f(E2[ib]);
        float s = u * si;
        #pragma unroll
        for (int o = 32; o > 0; o >>= 1) s += __shfl_xor(s, o, 64);
        neg_max = fmaxf(neg_max, s);
        neg_h  += fmaxf(s - 0.5f, 0.0f);
    }

    float delta = (neg_max - pos_min > 0.005f) ? 10.0f * (pos_min - neg_max) : 0.0f;
    float contrib = pos_h + (float)P_POS * neg_h + delta * (float)(B_USERS - wid);
    if (lane == 0) atomicAdd(acc, contrib);
}

__global__ void finalize(const float* __restrict__ acc, float* __restrict__ out) {
    out[0] = acc[0] / (float)B_USERS + 0.2f;
}

extern "C" void kernel_launch(void* const* d_in, const int* in_sizes, int n_in,
                              void* d_out, int out_size, void* d_ws, size_t ws_size,
                              hipStream_t stream) {
    const float* Eu0  = (const float*)d_in[0];
    const float* Ei0  = (const float*)d_in[1];
    const float* vals = (const float*)d_in[2];
    const int* rows = (const int*)d_in[7];
    const int* cols = (const int*)d_in[8];
    const int* uids = (const int*)d_in[9];
    const int* pos  = (const int*)d_in[10];
    const int* neg  = (const int*)d_in[11];
    int nnz = in_sizes[2];

    // workspace layout
    unsigned* edges  = (unsigned*)d_ws;                         // 2*nnz u32 (16MB)
    uint2*    stage  = (uint2*)(edges + (size_t)2 * nnz);       // NBUK*CAP uint2 (51MB)
    ushort*   E0b    = (ushort*)(stage + (size_t)NBUK * CAP);   // 3x NSEG*DIM bf16
    ushort*   E1b    = E0b + (size_t)NSEG * DIM;
    ushort*   E2b    = E1b + (size_t)NSEG * DIM;
    int*      cnt    = (int*)(E2b + (size_t)NSEG * DIM);        // NSEG
    int*      endo   = cnt + NSEG;                              // NSEG
    int*      bukoff = endo + NSEG;                             // NBUK
    int*      tails  = bukoff + NBUK;                           // NBUK   (zeroed)
    float*    acc    = (float*)(tails + NBUK);                  // 1      (zeroed)

    const int blk = 256;

    hipMemsetAsync(tails, 0, (NBUK + 1) * sizeof(int), stream);

    k_conv<<<(NSEG * (DIM / 2) + blk - 1) / blk, blk, 0, stream>>>(Eu0, Ei0, E0b);
    k_binA2<<<(nnz + EPB - 1) / EPB, 512, 0, stream>>>(vals, rows, cols, tails, stage, nnz);
    k_bscan<<<1, 1024, 0, stream>>>(tails, bukoff);
    k_binB2<<<NBUK, blk, 0, stream>>>(stage, tails, bukoff, edges, cnt, endo);

    const int prop_blocks = (NSEG * 64 + blk - 1) / blk;
    k_prop<<<prop_blocks, blk, 0, stream>>>(edges, endo, cnt, E0b, E1b);
    k_prop<<<prop_blocks, blk, 0, stream>>>(edges, endo, cnt, E1b, E2b);

    k_loss<<<(B_USERS * 64) / blk, blk, 0, stream>>>(E0b, E1b, E2b, uids, pos, neg, acc);
    finalize<<<1, 1, 0, stream>>>(acc, (float*)d_out);
}

// Round 12
// 260.865 us; speedup vs baseline: 6.5940x; 1.1424x over previous
//
#include <hip/hip_runtime.h>

#define N_U   50000
#define N_I   50000
#define NSEG  (N_U + N_I)      // row segments then col segments
#define DIM   64
#define B_USERS 1024
#define P_POS 10
#define N_NEG 40

#define BSEG  128                          // segments per bucket
#define NBUK  782                          // ceil(NSEG/BSEG)
#define CAP   8192                         // staging capacity per bucket (mean 5115)
#define EPB   8192                         // edges per binA2 block (512 thr x 16)

// f32 -> bf16 bits (RNE)
__device__ __forceinline__ unsigned f2b(float f) {
    unsigned b = __float_as_uint(f);
    return (b + 0x7FFFu + ((b >> 16) & 1u)) >> 16;
}
__device__ __forceinline__ float b2f(unsigned u) {
    return __uint_as_float(u << 16);
}
__device__ __forceinline__ float blo(unsigned u) { return __uint_as_float(u << 16); }
__device__ __forceinline__ float bhi(unsigned u) { return __uint_as_float(u & 0xFFFF0000u); }

// ---- convert Eu0||Ei0 (f32) into one concatenated bf16 table ----
__global__ void k_conv(const float* __restrict__ Eu0, const float* __restrict__ Ei0,
                       ushort* __restrict__ E0b) {
    int p = blockIdx.x * blockDim.x + threadIdx.x;
    if (p >= NSEG * (DIM / 2)) return;
    float2 v = (p < N_U * (DIM / 2)) ? ((const float2*)Eu0)[p]
                                     : ((const float2*)Ei0)[p - N_U * (DIM / 2)];
    ushort2 o;
    o.x = (ushort)f2b(v.x);
    o.y = (ushort)f2b(v.y);
    ((ushort2*)E0b)[p] = o;
}

// ---- binA2: bucket-append via LDS ranks + one fat global atomic per (block,bucket) ----
// record: x = nbr<<15 | val15 ; y = local segment (seg & 127)
__global__ __launch_bounds__(512) void k_binA2(const float* __restrict__ vals,
                                               const int* __restrict__ rows,
                                               const int* __restrict__ cols,
                                               int* __restrict__ tails,
                                               uint2* __restrict__ stage, int nnz) {
    __shared__ int hist[NBUK];
    __shared__ int base[NBUK];
    int t = threadIdx.x;
    for (int i = t; i < NBUK; i += 512) hist[i] = 0;
    __syncthreads();

    unsigned recx[32];
    unsigned meta[32];   // bucket<<20 | rank<<7 | lseg   (rank < 8192 fits 13 bits)
    int e0 = blockIdx.x * EPB;
    #pragma unroll
    for (int k = 0; k < 16; ++k) {
        int e = e0 + k * 512 + t;
        bool ok = e < nnz;
        int ee = ok ? e : 0;
        int r = rows[ee];
        int g = N_U + cols[ee];
        unsigned b = __float_as_uint(vals[ee]);
        unsigned v15 = ((b + 0x7FFFu + ((b >> 16) & 1u)) >> 16) & 0x7FFFu;
        if (ok) {
            int b0 = r >> 7;
            int rk0 = atomicAdd(&hist[b0], 1);
            recx[2 * k]     = (((unsigned)g) << 15) | v15;
            meta[2 * k]     = ((unsigned)b0 << 20) | ((unsigned)rk0 << 7) | (unsigned)(r & 127);
            int b1 = g >> 7;
            int rk1 = atomicAdd(&hist[b1], 1);
            recx[2 * k + 1] = (((unsigned)r) << 15) | v15;
            meta[2 * k + 1] = ((unsigned)b1 << 20) | ((unsigned)rk1 << 7) | (unsigned)(g & 127);
        } else {
            meta[2 * k] = 0xFFFFFFFFu;
            meta[2 * k + 1] = 0xFFFFFFFFu;
        }
    }
    __syncthreads();
    for (int i = t; i < NBUK; i += 512) {
        int h = hist[i];
        base[i] = h ? atomicAdd(&tails[i], h) : 0;
    }
    __syncthreads();
    #pragma unroll
    for (int k = 0; k < 32; ++k) {
        unsigned m = meta[k];
        if (m == 0xFFFFFFFFu) continue;
        int bkt  = m >> 20;
        int rank = (m >> 7) & 0x1FFF;
        int slot = base[bkt] + rank;
        if (slot < CAP) {
            uint2 rec;
            rec.x = recx[k];
            rec.y = m & 127u;
            stage[((size_t)bkt << 13) + slot] = rec;
        }
    }
}

// ---- exclusive scan of 782 bucket totals (single block) ----
__global__ __launch_bounds__(1024) void k_bscan(const int* __restrict__ tails,
                                                int* __restrict__ bukoff) {
    __shared__ int sh[1024];
    int t = threadIdx.x;
    int v = (t < NBUK) ? min(tails[t], CAP) : 0;
    sh[t] = v;
    __syncthreads();
    for (int o = 1; o < 1024; o <<= 1) {
        int x = (t >= o) ? sh[t - o] : 0;
        __syncthreads();
        sh[t] += x;
        __syncthreads();
    }
    if (t < NBUK) bukoff[t] = sh[t] - v;
}

// ---- binB2: per bucket, LDS 128-hist + scan, write cnt/endo, place edges ----
__global__ __launch_bounds__(256) void k_binB2(const uint2* __restrict__ stage,
                                               const int* __restrict__ tails,
                                               const int* __restrict__ bukoff,
                                               unsigned* __restrict__ edges,
                                               int* __restrict__ cnt,
                                               int* __restrict__ endo) {
    __shared__ int h[BSEG];
    __shared__ int sc[BSEG];
    __shared__ int cur[BSEG];
    int b = blockIdx.x, t = threadIdx.x;
    int cs = min(tails[b], CAP);
    size_t sbase = (size_t)b << 13;
    if (t < BSEG) h[t] = 0;
    __syncthreads();
    for (int i = t; i < cs; i += 256)
        atomicAdd(&h[stage[sbase + i].y], 1);
    __syncthreads();
    if (t < BSEG) sc[t] = h[t];
    __syncthreads();
    for (int o = 1; o < BSEG; o <<= 1) {
        int x = (t < BSEG && t >= o) ? sc[t - o] : 0;
        __syncthreads();
        if (t < BSEG) sc[t] += x;
        __syncthreads();
    }
    int seg0 = b * BSEG;
    if (t < BSEG) {
        int start = bukoff[b] + sc[t] - h[t];
        cur[t] = start;
        int seg = seg0 + t;
        if (seg < NSEG) { cnt[seg] = h[t]; endo[seg] = start + h[t]; }
    }
    __syncthreads();
    for (int i = t; i < cs; i += 256) {
        uint2 rec = stage[sbase + i];
        int pos = atomicAdd(&cur[rec.y], 1);
        edges[pos] = rec.x;
    }
}

// ---------------- propagation: one wave per segment, 8 edges/iter ----------------
// 8-lane groups: group q handles edge j+q; lane l7 loads uint4 = dims 8*l7..8*l7+7
__global__ __launch_bounds__(256) void k_prop(const unsigned* __restrict__ edges,
                                              const int* __restrict__ endo,
                                              const int* __restrict__ cnt,
                                              const ushort* __restrict__ Ecur,
                                              ushort* __restrict__ Enext) {
    int seg  = (blockIdx.x * blockDim.x + threadIdx.x) >> 6;
    int lane = threadIdx.x & 63;
    if (seg >= NSEG) return;
    int end = endo[seg], n = cnt[seg], start = end - n;
    int q  = lane >> 3;    // group 0..7
    int l7 = lane & 7;

    float a0 = 0.f, a1 = 0.f, a2 = 0.f, a3 = 0.f;
    float a4 = 0.f, a5 = 0.f, a6 = 0.f, a7 = 0.f;
    for (int b = 0; b < n; b += 64) {
        int k = b + lane;
        unsigned pk = (k < n) ? edges[start + k] : 0u;
        int m = min(n - b, 64);
        for (int j = 0; j < m; j += 8) {
            int sel = j + q;
            unsigned pj = __shfl(pk, sel, 64);
            float v = (sel < m) ? __uint_as_float((pj & 0x7FFFu) << 16) : 0.0f;
            unsigned idx = pj >> 15;
            uint4 ev = ((const uint4*)(Ecur + (size_t)idx * DIM))[l7];
            a0 = fmaf(v, blo(ev.x), a0); a1 = fmaf(v, bhi(ev.x), a1);
            a2 = fmaf(v, blo(ev.y), a2); a3 = fmaf(v, bhi(ev.y), a3);
            a4 = fmaf(v, blo(ev.z), a4); a5 = fmaf(v, bhi(ev.z), a5);
            a6 = fmaf(v, blo(ev.w), a6); a7 = fmaf(v, bhi(ev.w), a7);
        }
    }
    // reduce across the 8 groups (lane bits 3,4,5)
    a0 += __shfl_xor(a0, 8, 64);  a1 += __shfl_xor(a1, 8, 64);
    a2 += __shfl_xor(a2, 8, 64);  a3 += __shfl_xor(a3, 8, 64);
    a4 += __shfl_xor(a4, 8, 64);  a5 += __shfl_xor(a5, 8, 64);
    a6 += __shfl_xor(a6, 8, 64);  a7 += __shfl_xor(a7, 8, 64);
    a0 += __shfl_xor(a0, 16, 64); a1 += __shfl_xor(a1, 16, 64);
    a2 += __shfl_xor(a2, 16, 64); a3 += __shfl_xor(a3, 16, 64);
    a4 += __shfl_xor(a4, 16, 64); a5 += __shfl_xor(a5, 16, 64);
    a6 += __shfl_xor(a6, 16, 64); a7 += __shfl_xor(a7, 16, 64);
    a0 += __shfl_xor(a0, 32, 64); a1 += __shfl_xor(a1, 32, 64);
    a2 += __shfl_xor(a2, 32, 64); a3 += __shfl_xor(a3, 32, 64);
    a4 += __shfl_xor(a4, 32, 64); a5 += __shfl_xor(a5, 32, 64);
    a6 += __shfl_xor(a6, 32, 64); a7 += __shfl_xor(a7, 32, 64);
    if (q == 0) {
        uint4 ec = ((const uint4*)(Ecur + (size_t)seg * DIM))[l7];
        float z0 = a0 > 0.f ? a0 : 0.5f * a0;
        float z1 = a1 > 0.f ? a1 : 0.5f * a1;
        float z2 = a2 > 0.f ? a2 : 0.5f * a2;
        float z3 = a3 > 0.f ? a3 : 0.5f * a3;
        float z4 = a4 > 0.f ? a4 : 0.5f * a4;
        float z5 = a5 > 0.f ? a5 : 0.5f * a5;
        float z6 = a6 > 0.f ? a6 : 0.5f * a6;
        float z7 = a7 > 0.f ? a7 : 0.5f * a7;
        uint4 o;
        o.x = f2b(blo(ec.x) + z0) | (f2b(bhi(ec.x) + z1) << 16);
        o.y = f2b(blo(ec.y) + z2) | (f2b(bhi(ec.y) + z3) << 16);
        o.z = f2b(blo(ec.z) + z4) | (f2b(bhi(ec.z) + z5) << 16);
        o.w = f2b(blo(ec.w) + z6) | (f2b(bhi(ec.w) + z7) << 16);
        ((uint4*)(Enext + (size_t)seg * DIM))[l7] = o;
    }
}

// ---------------- loss ----------------
__global__ __launch_bounds__(256) void k_loss(const ushort* __restrict__ E0,
                                              const ushort* __restrict__ E1,
                                              const ushort* __restrict__ E2,
                                              const int* __restrict__ uids,
                                              const int* __restrict__ pos,
                                              const int* __restrict__ neg,
                                              float* __restrict__ acc) {
    int wid  = (blockIdx.x * blockDim.x + threadIdx.x) >> 6;
    int lane = threadIdx.x & 63;
    if (wid >= B_USERS) return;

    int uid = uids[wid];
    size_t ub = (size_t)uid * DIM + lane;
    float u = b2f(E0[ub]) + b2f(E1[ub]) + b2f(E2[ub]);

    float pos_min = 1e30f, pos_h = 0.0f;
    for (int p = 0; p < P_POS; ++p) {
        int it = pos[wid * P_POS + p];
        size_t ib = (size_t)(N_U + it) * DIM + lane;
        float si = b2f(E0[ib]) + b2f(E1[ib]) + b2f(E2[ib]);
        float s = u * si;
        #pragma unroll
        for (int o = 32; o > 0; o >>= 1) s += __shfl_xor(s, o, 64);
        pos_min = fminf(pos_min, s);
        pos_h  += fmaxf(1.0f - s, 0.0f);
    }

    float neg_max = -1e30f, neg_h = 0.0f;
    for (int nn = 0; nn < N_NEG; ++nn) {
        int it = neg[wid * N_NEG + nn];
        size_t ib = (size_t)(N_U + it) * DIM + lane;
        float si = b2f(E0[ib]) + b2f(E1[ib]) + b2f(E2[ib]);
        float s = u * si;
        #pragma unroll
        for (int o = 32; o > 0; o >>= 1) s += __shfl_xor(s, o, 64);
        neg_max = fmaxf(neg_max, s);
        neg_h  += fmaxf(s - 0.5f, 0.0f);
    }

    float delta = (neg_max - pos_min > 0.005f) ? 10.0f * (pos_min - neg_max) : 0.0f;
    float contrib = pos_h + (float)P_POS * neg_h + delta * (float)(B_USERS - wid);
    if (lane == 0) atomicAdd(acc, contrib);
}

__global__ void finalize(const float* __restrict__ acc, float* __restrict__ out) {
    out[0] = acc[0] / (float)B_USERS + 0.2f;
}

extern "C" void kernel_launch(void* const* d_in, const int* in_sizes, int n_in,
                              void* d_out, int out_size, void* d_ws, size_t ws_size,
                              hipStream_t stream) {
    const float* Eu0  = (const float*)d_in[0];
    const float* Ei0  = (const float*)d_in[1];
    const float* vals = (const float*)d_in[2];
    const int* rows = (const int*)d_in[7];
    const int* cols = (const int*)d_in[8];
    const int* uids = (const int*)d_in[9];
    const int* pos  = (const int*)d_in[10];
    const int* neg  = (const int*)d_in[11];
    int nnz = in_sizes[2];

    // workspace layout
    unsigned* edges  = (unsigned*)d_ws;                         // 2*nnz u32 (16MB)
    uint2*    stage  = (uint2*)(edges + (size_t)2 * nnz);       // NBUK*CAP uint2 (51MB)
    ushort*   E0b    = (ushort*)(stage + (size_t)NBUK * CAP);   // 3x NSEG*DIM bf16
    ushort*   E1b    = E0b + (size_t)NSEG * DIM;
    ushort*   E2b    = E1b + (size_t)NSEG * DIM;
    int*      cnt    = (int*)(E2b + (size_t)NSEG * DIM);        // NSEG
    int*      endo   = cnt + NSEG;                              // NSEG
    int*      bukoff = endo + NSEG;                             // NBUK
    int*      tails  = bukoff + NBUK;                           // NBUK   (zeroed)
    float*    acc    = (float*)(tails + NBUK);                  // 1      (zeroed)

    const int blk = 256;

    hipMemsetAsync(tails, 0, (NBUK + 1) * sizeof(int), stream);

    k_conv<<<(NSEG * (DIM / 2) + blk - 1) / blk, blk, 0, stream>>>(Eu0, Ei0, E0b);
    k_binA2<<<(nnz + EPB - 1) / EPB, 512, 0, stream>>>(vals, rows, cols, tails, stage, nnz);
    k_bscan<<<1, 1024, 0, stream>>>(tails, bukoff);
    k_binB2<<<NBUK, blk, 0, stream>>>(stage, tails, bukoff, edges, cnt, endo);

    const int prop_blocks = (NSEG * 64 + blk - 1) / blk;
    k_prop<<<prop_blocks, blk, 0, stream>>>(edges, endo, cnt, E0b, E1b);
    k_prop<<<prop_blocks, blk, 0, stream>>>(edges, endo, cnt, E1b, E2b);

    k_loss<<<(B_USERS * 64) / blk, blk, 0, stream>>>(E0b, E1b, E2b, uids, pos, neg, acc);
    finalize<<<1, 1, 0, stream>>>(acc, (float*)d_out);
}

// Round 13
// 249.232 us; speedup vs baseline: 6.9017x; 1.0467x over previous
//
#include <hip/hip_runtime.h>

#define N_U   50000
#define N_I   50000
#define NSEG  (N_U + N_I)      // row segments then col segments
#define DIM   64
#define B_USERS 1024
#define P_POS 10
#define N_NEG 40

#define BSEG  128                          // segments per bucket
#define NBUK  782                          // ceil(NSEG/BSEG)
#define CAP   8192                         // staging capacity per bucket (mean 5115)
#define EPB   8192                         // edges per binA2 block (512 thr x 16)

#ifndef __has_builtin
#define __has_builtin(x) 0
#endif
#if __has_builtin(__builtin_amdgcn_cvt_pk_f32_fp8) && __has_builtin(__builtin_amdgcn_cvt_pk_fp8_f32)
#define HAVE_FP8 1
#else
#define HAVE_FP8 0
#endif

typedef float f32x2 __attribute__((ext_vector_type(2)));

// f32 -> bf16 bits (RNE)
__device__ __forceinline__ unsigned f2b(float f) {
    unsigned b = __float_as_uint(f);
    return (b + 0x7FFFu + ((b >> 16) & 1u)) >> 16;
}
__device__ __forceinline__ float b2f(unsigned u) {
    return __uint_as_float(u << 16);
}
__device__ __forceinline__ float blo(unsigned u) { return __uint_as_float(u << 16); }
__device__ __forceinline__ float bhi(unsigned u) { return __uint_as_float(u & 0xFFFF0000u); }

#if !HAVE_FP8
// manual e4m3fn decode (denorm step 2^-9)
__device__ __forceinline__ float dec8(unsigned v) {
    unsigned s = (v >> 7) & 1u, ef = (v >> 3) & 0xFu, m = v & 7u;
    float r = (ef == 0u) ? (float)m * 0.001953125f
                         : __uint_as_float(((ef + 120u) << 23) | (m << 20));
    return s ? -r : r;
}
// manual e4m3fn encode, RNE, FTZ subnormals, clamp 448
__device__ __forceinline__ unsigned enc8(float f) {
    unsigned b = __float_as_uint(f);
    unsigned s = b >> 31;
    float a = fabsf(f);
    if (a >= 448.f) return (s << 7) | 0x7Eu;
    if (a < 0.015625f) return s << 7;
    int e = (int)((b >> 23) & 0xFF) - 120;           // fp8 exp field 1..15
    unsigned m = b & 0x7FFFFFu;
    unsigned keep = m >> 20, rem = m & 0xFFFFFu;
    keep += (rem > 0x80000u) || (rem == 0x80000u && (keep & 1u));
    if (keep == 8u) { keep = 0u; ++e; if (e > 15) return (s << 7) | 0x7Eu; }
    if (e == 15 && keep == 7u) keep = 6u;            // avoid NaN encoding
    return (s << 7) | ((unsigned)e << 3) | keep;
}
#endif

__device__ __forceinline__ void dec4(unsigned u, float& o0, float& o1, float& o2, float& o3) {
#if HAVE_FP8
    f32x2 a = __builtin_amdgcn_cvt_pk_f32_fp8((int)u, false);
    f32x2 b = __builtin_amdgcn_cvt_pk_f32_fp8((int)u, true);
    o0 = a.x; o1 = a.y; o2 = b.x; o3 = b.y;
#else
    o0 = dec8(u & 0xFFu); o1 = dec8((u >> 8) & 0xFFu);
    o2 = dec8((u >> 16) & 0xFFu); o3 = dec8(u >> 24);
#endif
}
__device__ __forceinline__ unsigned enc4(float f0, float f1, float f2, float f3) {
#if HAVE_FP8
    int w = 0;
    w = __builtin_amdgcn_cvt_pk_fp8_f32(f0, f1, w, false);
    w = __builtin_amdgcn_cvt_pk_fp8_f32(f2, f3, w, true);
    return (unsigned)w;
#else
    return enc8(f0) | (enc8(f1) << 8) | (enc8(f2) << 16) | (enc8(f3) << 24);
#endif
}

// ---- convert Eu0||Ei0 (f32) into bf16 table + fp8 shadow table ----
__global__ void k_conv(const float* __restrict__ Eu0, const float* __restrict__ Ei0,
                       ushort* __restrict__ E0b, unsigned* __restrict__ E0f8) {
    int p = blockIdx.x * blockDim.x + threadIdx.x;   // 4-dim group
    if (p >= NSEG * (DIM / 4)) return;
    float4 v = (p < N_U * (DIM / 4)) ? ((const float4*)Eu0)[p]
                                     : ((const float4*)Ei0)[p - N_U * (DIM / 4)];
    ushort4 o;
    o.x = (ushort)f2b(v.x); o.y = (ushort)f2b(v.y);
    o.z = (ushort)f2b(v.z); o.w = (ushort)f2b(v.w);
    ((ushort4*)E0b)[p] = o;
    E0f8[p] = enc4(v.x, v.y, v.z, v.w);
}

// ---- binA2: bucket-append via LDS ranks + one fat global atomic per (block,bucket) ----
__global__ __launch_bounds__(512) void k_binA2(const float* __restrict__ vals,
                                               const int* __restrict__ rows,
                                               const int* __restrict__ cols,
                                               int* __restrict__ tails,
                                               uint2* __restrict__ stage, int nnz) {
    __shared__ int hist[NBUK];
    __shared__ int base[NBUK];
    int t = threadIdx.x;
    for (int i = t; i < NBUK; i += 512) hist[i] = 0;
    __syncthreads();

    unsigned recx[32];
    unsigned meta[32];   // bucket<<20 | rank<<7 | lseg
    int e0 = blockIdx.x * EPB;
    #pragma unroll
    for (int k = 0; k < 16; ++k) {
        int e = e0 + k * 512 + t;
        bool ok = e < nnz;
        int ee = ok ? e : 0;
        int r = rows[ee];
        int g = N_U + cols[ee];
        unsigned b = __float_as_uint(vals[ee]);
        unsigned v15 = ((b + 0x7FFFu + ((b >> 16) & 1u)) >> 16) & 0x7FFFu;
        if (ok) {
            int b0 = r >> 7;
            int rk0 = atomicAdd(&hist[b0], 1);
            recx[2 * k]     = (((unsigned)g) << 15) | v15;
            meta[2 * k]     = ((unsigned)b0 << 20) | ((unsigned)rk0 << 7) | (unsigned)(r & 127);
            int b1 = g >> 7;
            int rk1 = atomicAdd(&hist[b1], 1);
            recx[2 * k + 1] = (((unsigned)r) << 15) | v15;
            meta[2 * k + 1] = ((unsigned)b1 << 20) | ((unsigned)rk1 << 7) | (unsigned)(g & 127);
        } else {
            meta[2 * k] = 0xFFFFFFFFu;
            meta[2 * k + 1] = 0xFFFFFFFFu;
        }
    }
    __syncthreads();
    for (int i = t; i < NBUK; i += 512) {
        int h = hist[i];
        base[i] = h ? atomicAdd(&tails[i], h) : 0;
    }
    __syncthreads();
    #pragma unroll
    for (int k = 0; k < 32; ++k) {
        unsigned m = meta[k];
        if (m == 0xFFFFFFFFu) continue;
        int bkt  = m >> 20;
        int rank = (m >> 7) & 0x1FFF;
        int slot = base[bkt] + rank;
        if (slot < CAP) {
            uint2 rec;
            rec.x = recx[k];
            rec.y = m & 127u;
            stage[((size_t)bkt << 13) + slot] = rec;
        }
    }
}

// ---- exclusive scan of 782 bucket totals (single block) ----
__global__ __launch_bounds__(1024) void k_bscan(const int* __restrict__ tails,
                                                int* __restrict__ bukoff) {
    __shared__ int sh[1024];
    int t = threadIdx.x;
    int v = (t < NBUK) ? min(tails[t], CAP) : 0;
    sh[t] = v;
    __syncthreads();
    for (int o = 1; o < 1024; o <<= 1) {
        int x = (t >= o) ? sh[t - o] : 0;
        __syncthreads();
        sh[t] += x;
        __syncthreads();
    }
    if (t < NBUK) bukoff[t] = sh[t] - v;
}

// ---- binB2: per bucket, LDS 128-hist + scan, write cnt/endo, place edges ----
__global__ __launch_bounds__(256) void k_binB2(const uint2* __restrict__ stage,
                                               const int* __restrict__ tails,
                                               const int* __restrict__ bukoff,
                                               unsigned* __restrict__ edges,
                                               int* __restrict__ cnt,
                                               int* __restrict__ endo) {
    __shared__ int h[BSEG];
    __shared__ int sc[BSEG];
    __shared__ int cur[BSEG];
    int b = blockIdx.x, t = threadIdx.x;
    int cs = min(tails[b], CAP);
    size_t sbase = (size_t)b << 13;
    if (t < BSEG) h[t] = 0;
    __syncthreads();
    for (int i = t; i < cs; i += 256)
        atomicAdd(&h[stage[sbase + i].y], 1);
    __syncthreads();
    if (t < BSEG) sc[t] = h[t];
    __syncthreads();
    for (int o = 1; o < BSEG; o <<= 1) {
        int x = (t < BSEG && t >= o) ? sc[t - o] : 0;
        __syncthreads();
        if (t < BSEG) sc[t] += x;
        __syncthreads();
    }
    int seg0 = b * BSEG;
    if (t < BSEG) {
        int start = bukoff[b] + sc[t] - h[t];
        cur[t] = start;
        int seg = seg0 + t;
        if (seg < NSEG) { cnt[seg] = h[t]; endo[seg] = start + h[t]; }
    }
    __syncthreads();
    for (int i = t; i < cs; i += 256) {
        uint2 rec = stage[sbase + i];
        int pos = atomicAdd(&cur[rec.y], 1);
        edges[pos] = rec.x;
    }
}

// ---------------- propagation: one wave per segment, 8 edges/iter ----------------
// gathers read fp8 shadow rows (64B = 1 line); self/output stay bf16.
template <int WF8>
__global__ __launch_bounds__(256) void k_prop(const unsigned* __restrict__ edges,
                                              const int* __restrict__ endo,
                                              const int* __restrict__ cnt,
                                              const ushort* __restrict__ Ecur,
                                              const unsigned* __restrict__ F8cur,
                                              ushort* __restrict__ Enext,
                                              unsigned* __restrict__ F8next) {
    int seg  = (blockIdx.x * blockDim.x + threadIdx.x) >> 6;
    int lane = threadIdx.x & 63;
    if (seg >= NSEG) return;
    int end = endo[seg], n = cnt[seg], start = end - n;
    int q  = lane >> 3;    // group 0..7
    int l7 = lane & 7;

    float a0 = 0.f, a1 = 0.f, a2 = 0.f, a3 = 0.f;
    float a4 = 0.f, a5 = 0.f, a6 = 0.f, a7 = 0.f;
    for (int b = 0; b < n; b += 64) {
        int k = b + lane;
        unsigned pk = (k < n) ? edges[start + k] : 0u;
        int m = min(n - b, 64);
        for (int j = 0; j < m; j += 8) {
            int sel = j + q;
            unsigned pj = __shfl(pk, sel, 64);
            float v = (sel < m) ? __uint_as_float((pj & 0x7FFFu) << 16) : 0.0f;
            unsigned idx = pj >> 15;
            uint2 ev = *(const uint2*)(F8cur + (size_t)idx * 16 + l7 * 2);
            float e0, e1, e2, e3, e4, e5, e6, e7;
            dec4(ev.x, e0, e1, e2, e3);
            dec4(ev.y, e4, e5, e6, e7);
            a0 = fmaf(v, e0, a0); a1 = fmaf(v, e1, a1);
            a2 = fmaf(v, e2, a2); a3 = fmaf(v, e3, a3);
            a4 = fmaf(v, e4, a4); a5 = fmaf(v, e5, a5);
            a6 = fmaf(v, e6, a6); a7 = fmaf(v, e7, a7);
        }
    }
    // reduce across the 8 groups (lane bits 3,4,5)
    a0 += __shfl_xor(a0, 8, 64);  a1 += __shfl_xor(a1, 8, 64);
    a2 += __shfl_xor(a2, 8, 64);  a3 += __shfl_xor(a3, 8, 64);
    a4 += __shfl_xor(a4, 8, 64);  a5 += __shfl_xor(a5, 8, 64);
    a6 += __shfl_xor(a6, 8, 64);  a7 += __shfl_xor(a7, 8, 64);
    a0 += __shfl_xor(a0, 16, 64); a1 += __shfl_xor(a1, 16, 64);
    a2 += __shfl_xor(a2, 16, 64); a3 += __shfl_xor(a3, 16, 64);
    a4 += __shfl_xor(a4, 16, 64); a5 += __shfl_xor(a5, 16, 64);
    a6 += __shfl_xor(a6, 16, 64); a7 += __shfl_xor(a7, 16, 64);
    a0 += __shfl_xor(a0, 32, 64); a1 += __shfl_xor(a1, 32, 64);
    a2 += __shfl_xor(a2, 32, 64); a3 += __shfl_xor(a3, 32, 64);
    a4 += __shfl_xor(a4, 32, 64); a5 += __shfl_xor(a5, 32, 64);
    a6 += __shfl_xor(a6, 32, 64); a7 += __shfl_xor(a7, 32, 64);
    if (q == 0) {
        uint4 ec = ((const uint4*)(Ecur + (size_t)seg * DIM))[l7];
        float r0 = blo(ec.x) + (a0 > 0.f ? a0 : 0.5f * a0);
        float r1 = bhi(ec.x) + (a1 > 0.f ? a1 : 0.5f * a1);
        float r2 = blo(ec.y) + (a2 > 0.f ? a2 : 0.5f * a2);
        float r3 = bhi(ec.y) + (a3 > 0.f ? a3 : 0.5f * a3);
        float r4 = blo(ec.z) + (a4 > 0.f ? a4 : 0.5f * a4);
        float r5 = bhi(ec.z) + (a5 > 0.f ? a5 : 0.5f * a5);
        float r6 = blo(ec.w) + (a6 > 0.f ? a6 : 0.5f * a6);
        float r7 = bhi(ec.w) + (a7 > 0.f ? a7 : 0.5f * a7);
        uint4 o;
        o.x = f2b(r0) | (f2b(r1) << 16);
        o.y = f2b(r2) | (f2b(r3) << 16);
        o.z = f2b(r4) | (f2b(r5) << 16);
        o.w = f2b(r6) | (f2b(r7) << 16);
        ((uint4*)(Enext + (size_t)seg * DIM))[l7] = o;
        if (WF8) {
            uint2 st;
            st.x = enc4(r0, r1, r2, r3);
            st.y = enc4(r4, r5, r6, r7);
            *(uint2*)(F8next + (size_t)seg * 16 + l7 * 2) = st;
        }
    }
}

// ---------------- loss (bf16 tables, unchanged) ----------------
__global__ __launch_bounds__(256) void k_loss(const ushort* __restrict__ E0,
                                              const ushort* __restrict__ E1,
                                              const ushort* __restrict__ E2,
                                              const int* __restrict__ uids,
                                              const int* __restrict__ pos,
                                              const int* __restrict__ neg,
                                              float* __restrict__ acc) {
    int wid  = (blockIdx.x * blockDim.x + threadIdx.x) >> 6;
    int lane = threadIdx.x & 63;
    if (wid >= B_USERS) return;

    int uid = uids[wid];
    size_t ub = (size_t)uid * DIM + lane;
    float u = b2f(E0[ub]) + b2f(E1[ub]) + b2f(E2[ub]);

    float pos_min = 1e30f, pos_h = 0.0f;
    for (int p = 0; p < P_POS; ++p) {
        int it = pos[wid * P_POS + p];
        size_t ib = (size_t)(N_U + it) * DIM + lane;
        float si = b2f(E0[ib]) + b2f(E1[ib]) + b2f(E2[ib]);
        float s = u * si;
        #pragma unroll
        for (int o = 32; o > 0; o >>= 1) s += __shfl_xor(s, o, 64);
        pos_min = fminf(pos_min, s);
        pos_h  += fmaxf(1.0f - s, 0.0f);
    }

    float neg_max = -1e30f, neg_h = 0.0f;
    for (int nn = 0; nn < N_NEG; ++nn) {
        int it = neg[wid * N_NEG + nn];
        size_t ib = (size_t)(N_U + it) * DIM + lane;
        float si = b2f(E0[ib]) + b2f(E1[ib]) + b2f(E2[ib]);
        float s = u * si;
        #pragma unroll
        for (int o = 32; o > 0; o >>= 1) s += __shfl_xor(s, o, 64);
        neg_max = fmaxf(neg_max, s);
        neg_h  += fmaxf(s - 0.5f, 0.0f);
    }

    float delta = (neg_max - pos_min > 0.005f) ? 10.0f * (pos_min - neg_max) : 0.0f;
    float contrib = pos_h + (float)P_POS * neg_h + delta * (float)(B_USERS - wid);
    if (lane == 0) atomicAdd(acc, contrib);
}

__global__ void finalize(const float* __restrict__ acc, float* __restrict__ out) {
    out[0] = acc[0] / (float)B_USERS + 0.2f;
}

extern "C" void kernel_launch(void* const* d_in, const int* in_sizes, int n_in,
                              void* d_out, int out_size, void* d_ws, size_t ws_size,
                              hipStream_t stream) {
    const float* Eu0  = (const float*)d_in[0];
    const float* Ei0  = (const float*)d_in[1];
    const float* vals = (const float*)d_in[2];
    const int* rows = (const int*)d_in[7];
    const int* cols = (const int*)d_in[8];
    const int* uids = (const int*)d_in[9];
    const int* pos  = (const int*)d_in[10];
    const int* neg  = (const int*)d_in[11];
    int nnz = in_sizes[2];

    // workspace layout
    unsigned* edges  = (unsigned*)d_ws;                         // 2*nnz u32 (16MB)
    uint2*    stage  = (uint2*)(edges + (size_t)2 * nnz);       // NBUK*CAP uint2 (51MB)
    ushort*   E0b    = (ushort*)(stage + (size_t)NBUK * CAP);   // 3x NSEG*DIM bf16 (38.4MB)
    ushort*   E1b    = E0b + (size_t)NSEG * DIM;
    ushort*   E2b    = E1b + (size_t)NSEG * DIM;
    unsigned* E0f8   = (unsigned*)(E2b + (size_t)NSEG * DIM);   // NSEG*16 u32 (6.4MB)
    unsigned* E1f8   = E0f8 + (size_t)NSEG * 16;                // 6.4MB
    int*      cnt    = (int*)(E1f8 + (size_t)NSEG * 16);        // NSEG
    int*      endo   = cnt + NSEG;                              // NSEG
    int*      bukoff = endo + NSEG;                             // NBUK
    int*      tails  = bukoff + NBUK;                           // NBUK   (zeroed)
    float*    acc    = (float*)(tails + NBUK);                  // 1      (zeroed)

    const int blk = 256;

    hipMemsetAsync(tails, 0, (NBUK + 1) * sizeof(int), stream);

    k_conv<<<(NSEG * (DIM / 4) + blk - 1) / blk, blk, 0, stream>>>(Eu0, Ei0, E0b, E0f8);
    k_binA2<<<(nnz + EPB - 1) / EPB, 512, 0, stream>>>(vals, rows, cols, tails, stage, nnz);
    k_bscan<<<1, 1024, 0, stream>>>(tails, bukoff);
    k_binB2<<<NBUK, blk, 0, stream>>>(stage, tails, bukoff, edges, cnt, endo);

    const int prop_blocks = (NSEG * 64 + blk - 1) / blk;
    k_prop<1><<<prop_blocks, blk, 0, stream>>>(edges, endo, cnt, E0b, E0f8, E1b, E1f8);
    k_prop<0><<<prop_blocks, blk, 0, stream>>>(edges, endo, cnt, E1b, E1f8, E2b, nullptr);

    k_loss<<<(B_USERS * 64) / blk, blk, 0, stream>>>(E0b, E1b, E2b, uids, pos, neg, acc);
    finalize<<<1, 1, 0, stream>>>(acc, (float*)d_out);
}

// Round 14
// 229.372 us; speedup vs baseline: 7.4993x; 1.0866x over previous
//
#include <hip/hip_runtime.h>

#define N_U   50000
#define N_I   50000
#define NSEG  (N_U + N_I)      // row segments then col segments
#define DIM   64
#define B_USERS 1024
#define P_POS 10
#define N_NEG 40

#define BSEG  128                          // segments per bucket
#define NBUK  782                          // ceil(NSEG/BSEG)
#define CAP   8192                         // staging capacity per bucket (mean 5115)
#define EPB   8192                         // edges per binA2 block (512 thr x 16)

#ifndef __has_builtin
#define __has_builtin(x) 0
#endif
#if __has_builtin(__builtin_amdgcn_cvt_pk_f32_fp8) && __has_builtin(__builtin_amdgcn_cvt_pk_fp8_f32)
#define HAVE_FP8 1
#else
#define HAVE_FP8 0
#endif

typedef float f32x2 __attribute__((ext_vector_type(2)));

// f32 -> bf16 bits (RNE)
__device__ __forceinline__ unsigned f2b(float f) {
    unsigned b = __float_as_uint(f);
    return (b + 0x7FFFu + ((b >> 16) & 1u)) >> 16;
}
__device__ __forceinline__ float b2f(unsigned u) {
    return __uint_as_float(u << 16);
}
__device__ __forceinline__ float blo(unsigned u) { return __uint_as_float(u << 16); }
__device__ __forceinline__ float bhi(unsigned u) { return __uint_as_float(u & 0xFFFF0000u); }

#if !HAVE_FP8
// manual e4m3fn decode (denorm step 2^-9)
__device__ __forceinline__ float dec8(unsigned v) {
    unsigned s = (v >> 7) & 1u, ef = (v >> 3) & 0xFu, m = v & 7u;
    float r = (ef == 0u) ? (float)m * 0.001953125f
                         : __uint_as_float(((ef + 120u) << 23) | (m << 20));
    return s ? -r : r;
}
// manual e4m3fn encode, RNE, FTZ subnormals, clamp 448
__device__ __forceinline__ unsigned enc8(float f) {
    unsigned b = __float_as_uint(f);
    unsigned s = b >> 31;
    float a = fabsf(f);
    if (a >= 448.f) return (s << 7) | 0x7Eu;
    if (a < 0.015625f) return s << 7;
    int e = (int)((b >> 23) & 0xFF) - 120;           // fp8 exp field 1..15
    unsigned m = b & 0x7FFFFFu;
    unsigned keep = m >> 20, rem = m & 0xFFFFFu;
    keep += (rem > 0x80000u) || (rem == 0x80000u && (keep & 1u));
    if (keep == 8u) { keep = 0u; ++e; if (e > 15) return (s << 7) | 0x7Eu; }
    if (e == 15 && keep == 7u) keep = 6u;            // avoid NaN encoding
    return (s << 7) | ((unsigned)e << 3) | keep;
}
#endif

__device__ __forceinline__ void dec4v(unsigned u, f32x2& p01, f32x2& p23) {
#if HAVE_FP8
    p01 = __builtin_amdgcn_cvt_pk_f32_fp8((int)u, false);
    p23 = __builtin_amdgcn_cvt_pk_f32_fp8((int)u, true);
#else
    p01.x = dec8(u & 0xFFu); p01.y = dec8((u >> 8) & 0xFFu);
    p23.x = dec8((u >> 16) & 0xFFu); p23.y = dec8(u >> 24);
#endif
}
__device__ __forceinline__ unsigned enc4(float f0, float f1, float f2, float f3) {
#if HAVE_FP8
    int w = 0;
    w = __builtin_amdgcn_cvt_pk_fp8_f32(f0, f1, w, false);
    w = __builtin_amdgcn_cvt_pk_fp8_f32(f2, f3, w, true);
    return (unsigned)w;
#else
    return enc8(f0) | (enc8(f1) << 8) | (enc8(f2) << 16) | (enc8(f3) << 24);
#endif
}

__device__ __forceinline__ void pkfma(f32x2& a, f32x2 b, f32x2 c) {
    asm("v_pk_fma_f32 %0, %1, %2, %0" : "+v"(a) : "v"(b), "v"(c));
}
__device__ __forceinline__ void pkadd(f32x2& a, f32x2 t) {
    asm("v_pk_add_f32 %0, %0, %1" : "+v"(a) : "v"(t));
}

// ---- convert Eu0||Ei0 (f32) into bf16 table + fp8 shadow table ----
__global__ void k_conv(const float* __restrict__ Eu0, const float* __restrict__ Ei0,
                       ushort* __restrict__ E0b, unsigned* __restrict__ E0f8) {
    int p = blockIdx.x * blockDim.x + threadIdx.x;   // 4-dim group
    if (p >= NSEG * (DIM / 4)) return;
    float4 v = (p < N_U * (DIM / 4)) ? ((const float4*)Eu0)[p]
                                     : ((const float4*)Ei0)[p - N_U * (DIM / 4)];
    ushort4 o;
    o.x = (ushort)f2b(v.x); o.y = (ushort)f2b(v.y);
    o.z = (ushort)f2b(v.z); o.w = (ushort)f2b(v.w);
    ((ushort4*)E0b)[p] = o;
    E0f8[p] = enc4(v.x, v.y, v.z, v.w);
}

// ---- binA2: bucket-append via LDS ranks + one fat global atomic per (block,bucket) ----
__global__ __launch_bounds__(512) void k_binA2(const float* __restrict__ vals,
                                               const int* __restrict__ rows,
                                               const int* __restrict__ cols,
                                               int* __restrict__ tails,
                                               uint2* __restrict__ stage, int nnz) {
    __shared__ int hist[NBUK];
    __shared__ int base[NBUK];
    int t = threadIdx.x;
    for (int i = t; i < NBUK; i += 512) hist[i] = 0;
    __syncthreads();

    unsigned recx[32];
    unsigned meta[32];   // bucket<<20 | rank<<7 | lseg
    int e0 = blockIdx.x * EPB;
    #pragma unroll
    for (int k = 0; k < 16; ++k) {
        int e = e0 + k * 512 + t;
        bool ok = e < nnz;
        int ee = ok ? e : 0;
        int r = rows[ee];
        int g = N_U + cols[ee];
        unsigned b = __float_as_uint(vals[ee]);
        unsigned v15 = ((b + 0x7FFFu + ((b >> 16) & 1u)) >> 16) & 0x7FFFu;
        if (ok) {
            int b0 = r >> 7;
            int rk0 = atomicAdd(&hist[b0], 1);
            recx[2 * k]     = (((unsigned)g) << 15) | v15;
            meta[2 * k]     = ((unsigned)b0 << 20) | ((unsigned)rk0 << 7) | (unsigned)(r & 127);
            int b1 = g >> 7;
            int rk1 = atomicAdd(&hist[b1], 1);
            recx[2 * k + 1] = (((unsigned)r) << 15) | v15;
            meta[2 * k + 1] = ((unsigned)b1 << 20) | ((unsigned)rk1 << 7) | (unsigned)(g & 127);
        } else {
            meta[2 * k] = 0xFFFFFFFFu;
            meta[2 * k + 1] = 0xFFFFFFFFu;
        }
    }
    __syncthreads();
    for (int i = t; i < NBUK; i += 512) {
        int h = hist[i];
        base[i] = h ? atomicAdd(&tails[i], h) : 0;
    }
    __syncthreads();
    #pragma unroll
    for (int k = 0; k < 32; ++k) {
        unsigned m = meta[k];
        if (m == 0xFFFFFFFFu) continue;
        int bkt  = m >> 20;
        int rank = (m >> 7) & 0x1FFF;
        int slot = base[bkt] + rank;
        if (slot < CAP) {
            uint2 rec;
            rec.x = recx[k];
            rec.y = m & 127u;
            stage[((size_t)bkt << 13) + slot] = rec;
        }
    }
}

// ---- exclusive scan of 782 bucket totals (single block) ----
__global__ __launch_bounds__(1024) void k_bscan(const int* __restrict__ tails,
                                                int* __restrict__ bukoff) {
    __shared__ int sh[1024];
    int t = threadIdx.x;
    int v = (t < NBUK) ? min(tails[t], CAP) : 0;
    sh[t] = v;
    __syncthreads();
    for (int o = 1; o < 1024; o <<= 1) {
        int x = (t >= o) ? sh[t - o] : 0;
        __syncthreads();
        sh[t] += x;
        __syncthreads();
    }
    if (t < NBUK) bukoff[t] = sh[t] - v;
}

// ---- binB2: per bucket, LDS 128-hist + scan, write cnt/endo, place edges ----
__global__ __launch_bounds__(256) void k_binB2(const uint2* __restrict__ stage,
                                               const int* __restrict__ tails,
                                               const int* __restrict__ bukoff,
                                               unsigned* __restrict__ edges,
                                               int* __restrict__ cnt,
                                               int* __restrict__ endo) {
    __shared__ int h[BSEG];
    __shared__ int sc[BSEG];
    __shared__ int cur[BSEG];
    int b = blockIdx.x, t = threadIdx.x;
    int cs = min(tails[b], CAP);
    size_t sbase = (size_t)b << 13;
    if (t < BSEG) h[t] = 0;
    __syncthreads();
    for (int i = t; i < cs; i += 256)
        atomicAdd(&h[stage[sbase + i].y], 1);
    __syncthreads();
    if (t < BSEG) sc[t] = h[t];
    __syncthreads();
    for (int o = 1; o < BSEG; o <<= 1) {
        int x = (t < BSEG && t >= o) ? sc[t - o] : 0;
        __syncthreads();
        if (t < BSEG) sc[t] += x;
        __syncthreads();
    }
    int seg0 = b * BSEG;
    if (t < BSEG) {
        int start = bukoff[b] + sc[t] - h[t];
        cur[t] = start;
        int seg = seg0 + t;
        if (seg < NSEG) { cnt[seg] = h[t]; endo[seg] = start + h[t]; }
    }
    __syncthreads();
    for (int i = t; i < cs; i += 256) {
        uint2 rec = stage[sbase + i];
        int pos = atomicAdd(&cur[rec.y], 1);
        edges[pos] = rec.x;
    }
}

// ---------------- propagation: 2 segments per wave (32 lanes each), 4 edges/iter ----
// gathers read fp8 shadow rows (64B = 1 line); self/output stay bf16.
// packed f32 math: 4 x f32x2 accumulators, v_pk_fma_f32.
template <int WF8>
__global__ __launch_bounds__(256) void k_prop(const unsigned* __restrict__ edges,
                                              const int* __restrict__ endo,
                                              const int* __restrict__ cnt,
                                              const ushort* __restrict__ Ecur,
                                              const unsigned* __restrict__ F8cur,
                                              ushort* __restrict__ Enext,
                                              unsigned* __restrict__ F8next) {
    int sid  = (blockIdx.x * blockDim.x + threadIdx.x) >> 5;   // segment, 2 per wave
    int lane = threadIdx.x & 63;
    if (sid >= NSEG) return;
    int l32  = lane & 31;
    int hbase = lane & 32;      // 0 or 32: this half's lane base
    int qq   = l32 >> 3;        // group 0..3 within half
    int l7   = lane & 7;
    int end = endo[sid], n = cnt[sid], start = end - n;

    f32x2 a0 = {0.f, 0.f}, a1 = {0.f, 0.f}, a2 = {0.f, 0.f}, a3 = {0.f, 0.f};
    for (int b = 0; b < n; b += 32) {
        int k = b + l32;
        unsigned pk = (k < n) ? edges[start + k] : 0u;
        int m = min(n - b, 32);
        for (int j = 0; j < m; j += 4) {
            int sel = j + qq;
            unsigned pj = __shfl(pk, hbase + sel, 64);
            float v = (sel < m) ? __uint_as_float((pj & 0x7FFFu) << 16) : 0.0f;
            unsigned idx = pj >> 15;
            uint2 ev = *(const uint2*)(F8cur + (size_t)idx * 16 + l7 * 2);
            f32x2 e01, e23, e45, e67;
            dec4v(ev.x, e01, e23);
            dec4v(ev.y, e45, e67);
            f32x2 vv = {v, v};
            pkfma(a0, vv, e01);
            pkfma(a1, vv, e23);
            pkfma(a2, vv, e45);
            pkfma(a3, vv, e67);
        }
    }
    // reduce across the 4 groups of this half (lane bits 3,4)
    #pragma unroll
    for (int off = 8; off <= 16; off <<= 1) {
        f32x2 t;
        t.x = __shfl_xor(a0.x, off, 64); t.y = __shfl_xor(a0.y, off, 64); pkadd(a0, t);
        t.x = __shfl_xor(a1.x, off, 64); t.y = __shfl_xor(a1.y, off, 64); pkadd(a1, t);
        t.x = __shfl_xor(a2.x, off, 64); t.y = __shfl_xor(a2.y, off, 64); pkadd(a2, t);
        t.x = __shfl_xor(a3.x, off, 64); t.y = __shfl_xor(a3.y, off, 64); pkadd(a3, t);
    }
    if (qq == 0) {
        uint4 ec = ((const uint4*)(Ecur + (size_t)sid * DIM))[l7];
        float r0 = blo(ec.x) + (a0.x > 0.f ? a0.x : 0.5f * a0.x);
        float r1 = bhi(ec.x) + (a0.y > 0.f ? a0.y : 0.5f * a0.y);
        float r2 = blo(ec.y) + (a1.x > 0.f ? a1.x : 0.5f * a1.x);
        float r3 = bhi(ec.y) + (a1.y > 0.f ? a1.y : 0.5f * a1.y);
        float r4 = blo(ec.z) + (a2.x > 0.f ? a2.x : 0.5f * a2.x);
        float r5 = bhi(ec.z) + (a2.y > 0.f ? a2.y : 0.5f * a2.y);
        float r6 = blo(ec.w) + (a3.x > 0.f ? a3.x : 0.5f * a3.x);
        float r7 = bhi(ec.w) + (a3.y > 0.f ? a3.y : 0.5f * a3.y);
        uint4 o;
        o.x = f2b(r0) | (f2b(r1) << 16);
        o.y = f2b(r2) | (f2b(r3) << 16);
        o.z = f2b(r4) | (f2b(r5) << 16);
        o.w = f2b(r6) | (f2b(r7) << 16);
        ((uint4*)(Enext + (size_t)sid * DIM))[l7] = o;
        if (WF8) {
            uint2 st;
            st.x = enc4(r0, r1, r2, r3);
            st.y = enc4(r4, r5, r6, r7);
            *(uint2*)(F8next + (size_t)sid * 16 + l7 * 2) = st;
        }
    }
}

// ---------------- loss (bf16 tables, unchanged) ----------------
__global__ __launch_bounds__(256) void k_loss(const ushort* __restrict__ E0,
                                              const ushort* __restrict__ E1,
                                              const ushort* __restrict__ E2,
                                              const int* __restrict__ uids,
                                              const int* __restrict__ pos,
                                              const int* __restrict__ neg,
                                              float* __restrict__ acc) {
    int wid  = (blockIdx.x * blockDim.x + threadIdx.x) >> 6;
    int lane = threadIdx.x & 63;
    if (wid >= B_USERS) return;

    int uid = uids[wid];
    size_t ub = (size_t)uid * DIM + lane;
    float u = b2f(E0[ub]) + b2f(E1[ub]) + b2f(E2[ub]);

    float pos_min = 1e30f, pos_h = 0.0f;
    for (int p = 0; p < P_POS; ++p) {
        int it = pos[wid * P_POS + p];
        size_t ib = (size_t)(N_U + it) * DIM + lane;
        float si = b2f(E0[ib]) + b2f(E1[ib]) + b2f(E2[ib]);
        float s = u * si;
        #pragma unroll
        for (int o = 32; o > 0; o >>= 1) s += __shfl_xor(s, o, 64);
        pos_min = fminf(pos_min, s);
        pos_h  += fmaxf(1.0f - s, 0.0f);
    }

    float neg_max = -1e30f, neg_h = 0.0f;
    for (int nn = 0; nn < N_NEG; ++nn) {
        int it = neg[wid * N_NEG + nn];
        size_t ib = (size_t)(N_U + it) * DIM + lane;
        float si = b2f(E0[ib]) + b2f(E1[ib]) + b2f(E2[ib]);
        float s = u * si;
        #pragma unroll
        for (int o = 32; o > 0; o >>= 1) s += __shfl_xor(s, o, 64);
        neg_max = fmaxf(neg_max, s);
        neg_h  += fmaxf(s - 0.5f, 0.0f);
    }

    float delta = (neg_max - pos_min > 0.005f) ? 10.0f * (pos_min - neg_max) : 0.0f;
    float contrib = pos_h + (float)P_POS * neg_h + delta * (float)(B_USERS - wid);
    if (lane == 0) atomicAdd(acc, contrib);
}

__global__ void finalize(const float* __restrict__ acc, float* __restrict__ out) {
    out[0] = acc[0] / (float)B_USERS + 0.2f;
}

extern "C" void kernel_launch(void* const* d_in, const int* in_sizes, int n_in,
                              void* d_out, int out_size, void* d_ws, size_t ws_size,
                              hipStream_t stream) {
    const float* Eu0  = (const float*)d_in[0];
    const float* Ei0  = (const float*)d_in[1];
    const float* vals = (const float*)d_in[2];
    const int* rows = (const int*)d_in[7];
    const int* cols = (const int*)d_in[8];
    const int* uids = (const int*)d_in[9];
    const int* pos  = (const int*)d_in[10];
    const int* neg  = (const int*)d_in[11];
    int nnz = in_sizes[2];

    // workspace layout
    unsigned* edges  = (unsigned*)d_ws;                         // 2*nnz u32 (16MB)
    uint2*    stage  = (uint2*)(edges + (size_t)2 * nnz);       // NBUK*CAP uint2 (51MB)
    ushort*   E0b    = (ushort*)(stage + (size_t)NBUK * CAP);   // 3x NSEG*DIM bf16 (38.4MB)
    ushort*   E1b    = E0b + (size_t)NSEG * DIM;
    ushort*   E2b    = E1b + (size_t)NSEG * DIM;
    unsigned* E0f8   = (unsigned*)(E2b + (size_t)NSEG * DIM);   // NSEG*16 u32 (6.4MB)
    unsigned* E1f8   = E0f8 + (size_t)NSEG * 16;                // 6.4MB
    int*      cnt    = (int*)(E1f8 + (size_t)NSEG * 16);        // NSEG
    int*      endo   = cnt + NSEG;                              // NSEG
    int*      bukoff = endo + NSEG;                             // NBUK
    int*      tails  = bukoff + NBUK;                           // NBUK   (zeroed)
    float*    acc    = (float*)(tails + NBUK);                  // 1      (zeroed)

    const int blk = 256;

    hipMemsetAsync(tails, 0, (NBUK + 1) * sizeof(int), stream);

    k_conv<<<(NSEG * (DIM / 4) + blk - 1) / blk, blk, 0, stream>>>(Eu0, Ei0, E0b, E0f8);
    k_binA2<<<(nnz + EPB - 1) / EPB, 512, 0, stream>>>(vals, rows, cols, tails, stage, nnz);
    k_bscan<<<1, 1024, 0, stream>>>(tails, bukoff);
    k_binB2<<<NBUK, blk, 0, stream>>>(stage, tails, bukoff, edges, cnt, endo);

    const int prop_blocks = (NSEG * 32 + blk - 1) / blk;
    k_prop<1><<<prop_blocks, blk, 0, stream>>>(edges, endo, cnt, E0b, E0f8, E1b, E1f8);
    k_prop<0><<<prop_blocks, blk, 0, stream>>>(edges, endo, cnt, E1b, E1f8, E2b, nullptr);

    k_loss<<<(B_USERS * 64) / blk, blk, 0, stream>>>(E0b, E1b, E2b, uids, pos, neg, acc);
    finalize<<<1, 1, 0, stream>>>(acc, (float*)d_out);
}